// Round 15
// baseline (532.795 us; speedup 1.0000x reference)
//
#include <hip/hip_runtime.h>
#include <hip/hip_bf16.h>

#define T_TOK 4096
#define DM 1024
#define DH 4096
#define NE 8
#define NSLOT (T_TOK * 2)            // compact slots: exactly sum(cnt)
#define MAXTILES 72
#define WELEMS ((size_t)NE * DH * DM)

typedef __attribute__((ext_vector_type(4))) float fl4;
typedef __attribute__((ext_vector_type(8))) short sh8;
typedef __attribute__((ext_vector_type(8))) unsigned short us8;
typedef unsigned short u16;

__device__ __forceinline__ u16 f2bf(float f) {
  __hip_bfloat16 h = __float2bfloat16(f);
  return __builtin_bit_cast(u16, h);
}

// tanh-GELU via hardware exp (passed r14 with absmax 0.0156)
__device__ __forceinline__ float gelu_tanh(float x) {
  float u = 0.7978845608028654f * (x + 0.044715f * x * x * x);
  u = fminf(fmaxf(u, -15.f), 15.f);
  float ez = __expf(2.f * u);
  return 0.5f * x * (1.f + (ez - 1.f) / (ez + 1.f));
}

__device__ __forceinline__ void gload_lds16(const void* g, void* l) {
  __builtin_amdgcn_global_load_lds(
      (const __attribute__((address_space(1))) unsigned int*)g,
      (__attribute__((address_space(3))) unsigned int*)l, 16, 0, 0);
}

template <int N>
__device__ __forceinline__ void wait_vmcnt() {
  if constexpr (N == 0) asm volatile("s_waitcnt vmcnt(0)" ::: "memory");
  else if constexpr (N == 4) asm volatile("s_waitcnt vmcnt(4)" ::: "memory");
}

// ---------------- weight fp32 -> bf16 (both tensors, one full-BW pass) -------
__global__ __launch_bounds__(256) void wconv_kernel(
    const float* __restrict__ w1, const float* __restrict__ w2,
    u16* __restrict__ w1b, u16* __restrict__ w2b) {
  size_t i = ((size_t)blockIdx.x * 256 + threadIdx.x) * 8;  // grid covers WELEMS
  fl4 a0 = *(const fl4*)(w1 + i);
  fl4 a1 = *(const fl4*)(w1 + i + 4);
  fl4 b0 = *(const fl4*)(w2 + i);
  fl4 b1 = *(const fl4*)(w2 + i + 4);
  us8 oa, ob;
#pragma unroll
  for (int j = 0; j < 4; j++) {
    oa[j] = f2bf(a0[j]); oa[j + 4] = f2bf(a1[j]);
    ob[j] = f2bf(b0[j]); ob[j + 4] = f2bf(b1[j]);
  }
  *(us8*)(w1b + i) = oa;
  *(us8*)(w2b + i) = ob;
}

// ---------------- router: logits + top-2 (no xbf write) ----------------
__global__ __launch_bounds__(256) void router_kernel(
    const float* __restrict__ x, const float* __restrict__ rw,
    int* __restrict__ tok_e, float* __restrict__ tok_w, int* __restrict__ ctl) {
  int tid = threadIdx.x;
  int wv = tid >> 6, lane = tid & 63;
  int t = blockIdx.x * 4 + wv;
  if (t >= T_TOK) return;

  const float* xp = x + (size_t)t * DM + lane * 16;
  fl4 xq[4];
#pragma unroll
  for (int i = 0; i < 4; i++) xq[i] = *(const fl4*)(xp + i * 4);

  float acc8[NE];
#pragma unroll
  for (int e = 0; e < NE; e++) {
    const float* wp = rw + (size_t)e * DM + lane * 16;
    float s = 0.f;
#pragma unroll
    for (int i = 0; i < 4; i++) {
      fl4 w4 = *(const fl4*)(wp + i * 4);
      s += xq[i][0] * w4[0] + xq[i][1] * w4[1] + xq[i][2] * w4[2] + xq[i][3] * w4[3];
    }
    acc8[e] = s;
  }
#pragma unroll
  for (int e = 0; e < NE; e++) {
#pragma unroll
    for (int off = 32; off > 0; off >>= 1) acc8[e] += __shfl_xor(acc8[e], off);
  }
  if (lane == 0) {
    float v1 = -1e30f, v2 = -1e30f;
    int i1 = 0, i2 = 0;
#pragma unroll
    for (int e = 0; e < NE; e++) {
      float v = acc8[e];
      if (v > v1) { v2 = v1; i2 = i1; v1 = v; i1 = e; }
      else if (v > v2) { v2 = v; i2 = e; }
    }
    float ex = expf(v2 - v1);
    float s = 1.0f + ex;
    tok_e[t * 2] = i1; tok_e[t * 2 + 1] = i2;
    tok_w[t * 2] = 1.0f / s; tok_w[t * 2 + 1] = ex / s;
    atomicAdd(&ctl[i1], 1);
    atomicAdd(&ctl[i2], 1);
  }
}

// ctl: [0..7] counts, [8..15] cursors (padded), [16..23] padded bases,
// [24..31] compact bases, [32..103] tile_expert (padded-space 128-tiles)
__global__ __launch_bounds__(128) void scan_kernel(int* __restrict__ ctl) {
  __shared__ int base_s[NE], cbase_s[NE];
  __shared__ int tb_s[NE + 1];
  int tid = threadIdx.x;
  if (tid == 0) {
    int s = 0, cs = 0, tb = 0;
    for (int e = 0; e < NE; e++) {
      base_s[e] = s;
      cbase_s[e] = cs;
      tb_s[e] = tb;
      int c = ctl[e];
      int nte = (c + 127) >> 7;
      tb += nte;
      s += nte << 7;
      cs += c;
    }
    tb_s[NE] = tb;
  }
  __syncthreads();
  if (tid < NE) {
    ctl[16 + tid] = base_s[tid];
    ctl[8 + tid] = base_s[tid];
    ctl[24 + tid] = cbase_s[tid];
  }
  if (tid < MAXTILES) {
    int e = -1;
#pragma unroll
    for (int k = 0; k < NE; k++)
      if (tid >= tb_s[k] && tid < tb_s[k + 1]) e = k;
    ctl[32 + tid] = e;
  }
}

// assign: padded cursor -> compact slot; tok_map_c[cslot]=t; islot[t,k]=cslot
__global__ __launch_bounds__(256) void assign_kernel(
    const int* __restrict__ tok_e, int* __restrict__ ctl,
    int* __restrict__ tok_map_c, int* __restrict__ islot) {
  int t = blockIdx.x * 256 + threadIdx.x;
  if (t < T_TOK) {
#pragma unroll
    for (int k = 0; k < 2; k++) {
      int e = tok_e[t * 2 + k];
      int slot = atomicAdd(&ctl[8 + e], 1);            // padded slot
      int cslot = slot - ctl[16 + e] + ctl[24 + e];    // compact slot
      tok_map_c[cslot] = t;
      islot[t * 2 + k] = cslot;
    }
  }
}

// gather: xg[c] = bf16(x[tok_map_c[c]]) — all NSLOT compact slots are written
__global__ __launch_bounds__(256) void gather_kernel(
    const float* __restrict__ x, const int* __restrict__ tok_map_c,
    u16* __restrict__ xg) {
  int c = blockIdx.x * 2 + (threadIdx.x >> 7);
  int li = threadIdx.x & 127;
  int t = tok_map_c[c];
  const float* xp = x + (size_t)t * DM + li * 8;
  fl4 v0 = *(const fl4*)xp;
  fl4 v1 = *(const fl4*)(xp + 4);
  us8 o;
#pragma unroll
  for (int j = 0; j < 4; j++) { o[j] = f2bf(v0[j]); o[j + 4] = f2bf(v1[j]); }
  *(us8*)(xg + (size_t)c * DM + li * 8) = o;
}

// combine: out[t] = sum_k w_k * (y[islot_c] + b2[e_k])
__global__ __launch_bounds__(256) void combine_kernel(
    const float* __restrict__ y, const float* __restrict__ b2,
    const int* __restrict__ tok_e, const int* __restrict__ islot,
    const float* __restrict__ tok_w, float* __restrict__ out) {
  int idx = blockIdx.x * 256 + threadIdx.x;
  int t = idx >> 8;
  int c4 = (idx & 255) * 4;
  int e0 = tok_e[t * 2], e1 = tok_e[t * 2 + 1];
  int s0 = islot[t * 2], s1 = islot[t * 2 + 1];
  float w0 = tok_w[t * 2], w1 = tok_w[t * 2 + 1];
  fl4 y0 = *(const fl4*)(y + (size_t)s0 * DM + c4);
  fl4 y1 = *(const fl4*)(y + (size_t)s1 * DM + c4);
  fl4 bb0 = *(const fl4*)(b2 + (size_t)e0 * DM + c4);
  fl4 bb1 = *(const fl4*)(b2 + (size_t)e1 * DM + c4);
  fl4 o;
#pragma unroll
  for (int i = 0; i < 4; i++) o[i] = w0 * (y0[i] + bb0[i]) + w1 * (y1[i] + bb1[i]);
  *(fl4*)(out + (size_t)t * DM + c4) = o;
}

// ---- grouped GEMM: 128x128, BK=32, 4 waves, r11 counted-vmcnt dbuf loop -----
// A LINEAR for both (fc1: compact xg; fc2: compact H). Tiles live in padded
// slot space; storage rows are compact via hbase = cbase - base.
// fc2: K-split 2-way, atomicAdd partials into pre-zeroed compact y.
template <bool FC1>
__global__ __launch_bounds__(256, 4) void moe_gemm(
    const u16* __restrict__ Ab, const u16* __restrict__ Wb,
    const float* __restrict__ bias, u16* __restrict__ Hout,
    float* __restrict__ Yout, const int* __restrict__ ctl) {
  constexpr int KTOT = FC1 ? DM : DH;
  constexpr int NTOT = FC1 ? DH : DM;
  constexpr int NKL = FC1 ? 32 : 64;

  int bid = blockIdx.x;
  int x = bid & 7, idx = bid >> 3;
  int tl = idx % 9, pn = idx / 9;
  int nt, ks;
  if (FC1) { nt = pn; ks = 0; }
  else     { nt = pn >> 1; ks = pn & 1; }
  int tile = x * 9 + tl;

  int e = ctl[32 + tile];
  if (e < 0) return;
  int cnt = ctl[e], base = ctl[16 + e], cbase = ctl[24 + e];
  int hbase = cbase - base;        // padded slot + hbase = compact row
  int cmax = cbase + cnt - 1;      // last valid compact row for this expert
  int m0 = tile * 128;             // padded slot of tile row 0

  __shared__ u16 As[2][128 * 32];
  __shared__ u16 Bs[2][128 * 32];

  int tid = threadIdx.x;
  int wv = tid >> 6, lane = tid & 63;
  int wr = wv >> 1, wc = wv & 1;
  int khalf = lane >> 4, l15 = lane & 15;

  const u16* asrc[2];
  const u16* bsrc[2];
#pragma unroll
  for (int r2 = 0; r2 < 2; r2++) {
    int c = r2 * 256 + tid;
    int row = c >> 2, q = c & 3;
    int qs = q ^ ((row >> 2) & 3);
    int crow = m0 + row + hbase;
    if (crow > cmax) crow = cmax;  // pad rows: any valid row (masked on store)
    asrc[r2] = Ab + (size_t)crow * KTOT + ks * 2048 + qs * 8;
    bsrc[r2] = Wb + ((size_t)e * NTOT + nt * 128 + row) * KTOT + ks * 2048 + qs * 8;
  }

#define STAGE(B, KT)                                                         \
  { _Pragma("unroll") for (int r2 = 0; r2 < 2; r2++) {                       \
      gload_lds16(asrc[r2] + (KT) * 32, &As[B][(r2 * 256 + wv * 64) * 8]);   \
      gload_lds16(bsrc[r2] + (KT) * 32, &Bs[B][(r2 * 256 + wv * 64) * 8]);   \
    } }

  int aoff[4], boff[4];
#pragma unroll
  for (int m = 0; m < 4; m++) {
    int rowl = wr * 64 + m * 16 + l15;
    aoff[m] = rowl * 64 + ((khalf * 16) ^ ((rowl & 12) << 2));
  }
#pragma unroll
  for (int n = 0; n < 4; n++) {
    int coll = wc * 64 + n * 16 + l15;
    boff[n] = coll * 64 + ((khalf * 16) ^ ((coll & 12) << 2));
  }

  fl4 acc[4][4];
#pragma unroll
  for (int m = 0; m < 4; m++)
#pragma unroll
    for (int n = 0; n < 4; n++) acc[m][n] = (fl4){0.f, 0.f, 0.f, 0.f};

#define COMPUTE(B)                                                           \
  {                                                                          \
    sh8 af[4], bfr[4];                                                       \
    _Pragma("unroll") for (int m = 0; m < 4; m++)                            \
      af[m] = *(const sh8*)((const char*)As[B] + aoff[m]);                   \
    _Pragma("unroll") for (int n = 0; n < 4; n++)                            \
      bfr[n] = *(const sh8*)((const char*)Bs[B] + boff[n]);                  \
    __builtin_amdgcn_s_setprio(1);                                           \
    _Pragma("unroll") for (int m = 0; m < 4; m++)                            \
    _Pragma("unroll") for (int n = 0; n < 4; n++)                            \
      acc[m][n] = __builtin_amdgcn_mfma_f32_16x16x32_bf16(af[m], bfr[n],     \
                                                          acc[m][n], 0, 0, 0); \
    __builtin_amdgcn_s_setprio(0);                                           \
  }

  STAGE(0, 0);
  for (int kt = 0; kt < NKL; kt += 2) {
    STAGE(1, kt + 1);
    wait_vmcnt<4>();
    __builtin_amdgcn_s_barrier();
    COMPUTE(0);
    __builtin_amdgcn_s_barrier();
    if (kt + 2 < NKL) {
      STAGE(0, kt + 2);
      wait_vmcnt<4>();
    } else {
      wait_vmcnt<0>();
    }
    __builtin_amdgcn_s_barrier();
    COMPUTE(1);
    __builtin_amdgcn_s_barrier();
  }

  if (FC1) {
#pragma unroll
    for (int n = 0; n < 4; n++) {
      int colg = nt * 128 + wc * 64 + n * 16 + l15;
      float bn = bias[(size_t)e * DH + colg];
#pragma unroll
      for (int m = 0; m < 4; m++) {
#pragma unroll
        for (int j = 0; j < 4; j++) {
          int crow = m0 + wr * 64 + m * 16 + khalf * 4 + j + hbase;
          if (crow <= cmax) {
            float v = acc[m][n][j] + bn;
            Hout[(size_t)crow * DH + colg] = f2bf(gelu_tanh(v));
          }
        }
      }
    }
  } else {
#pragma unroll
    for (int m = 0; m < 4; m++) {
#pragma unroll
      for (int j = 0; j < 4; j++) {
        int crow = m0 + wr * 64 + m * 16 + khalf * 4 + j + hbase;
        if (crow <= cmax) {
#pragma unroll
          for (int n = 0; n < 4; n++) {
            int colg = nt * 128 + wc * 64 + n * 16 + l15;
            atomicAdd(&Yout[(size_t)crow * DM + colg], acc[m][n][j]);
          }
        }
      }
    }
  }
#undef STAGE
#undef COMPUTE
}

extern "C" void kernel_launch(void* const* d_in, const int* in_sizes, int n_in,
                              void* d_out, int out_size, void* d_ws, size_t ws_size,
                              hipStream_t stream) {
  const float* x  = (const float*)d_in[0];
  const float* rw = (const float*)d_in[1];
  const float* w1 = (const float*)d_in[2];
  const float* b1 = (const float*)d_in[3];
  const float* w2 = (const float*)d_in[4];
  const float* b2 = (const float*)d_in[5];
  float* out = (float*)d_out;

  char* ws = (char*)d_ws;
  size_t off = 0;
  u16* xg  = (u16*)(ws + off); off += (size_t)NSLOT * DM * 2;   // 16.8 MB
  u16* H   = (u16*)(ws + off); off += (size_t)NSLOT * DH * 2;   // 67.1 MB
  u16* w1b = (u16*)(ws + off); off += WELEMS * 2;               // 67.1 MB
  u16* w2b = (u16*)(ws + off); off += WELEMS * 2;               // 67.1 MB
  int* tok_map_c = (int*)(ws + off); off += (size_t)NSLOT * 4;
  int* tok_e     = (int*)(ws + off); off += (size_t)T_TOK * 8;
  float* tok_w   = (float*)(ws + off); off += (size_t)T_TOK * 8;
  int* islot     = (int*)(ws + off); off += (size_t)T_TOK * 8;
  int* ctl       = (int*)(ws + off); off += 512;
  // y (compact fp32, 33.6 MB) overlays w1b (dead after fc1)
  float* y = (float*)w1b;

  hipMemsetAsync(ctl, 0, 128 * 4, stream);

  router_kernel<<<T_TOK / 4, 256, 0, stream>>>(x, rw, tok_e, tok_w, ctl);
  scan_kernel<<<1, 128, 0, stream>>>(ctl);
  assign_kernel<<<T_TOK / 256, 256, 0, stream>>>(tok_e, ctl, tok_map_c, islot);
  gather_kernel<<<NSLOT / 2, 256, 0, stream>>>(x, tok_map_c, xg);
  wconv_kernel<<<WELEMS / (256 * 8), 256, 0, stream>>>(w1, w2, w1b, w2b);

  moe_gemm<true><<<8 * 9 * 32, 256, 0, stream>>>(xg, w1b, b1, H, nullptr, ctl);

  hipMemsetAsync(y, 0, (size_t)NSLOT * DM * 4, stream);  // w1b dead after fc1
  moe_gemm<false><<<8 * 9 * 16, 256, 0, stream>>>(H, w2b, nullptr, nullptr, y, ctl);
  combine_kernel<<<T_TOK * DM / 4 / 256, 256, 0, stream>>>(
      y, b2, tok_e, islot, tok_w, out);
}

// Round 16
// 462.543 us; speedup vs baseline: 1.1519x; 1.1519x over previous
//
#include <hip/hip_runtime.h>
#include <hip/hip_bf16.h>

#define T_TOK 4096
#define DM 1024
#define DH 4096
#define NE 8
#define NSLOT (T_TOK * 2)            // compact slots: exactly sum(cnt)
#define MAXTILES 72
#define WELEMS ((size_t)NE * DH * DM)

typedef __attribute__((ext_vector_type(4))) float fl4;
typedef __attribute__((ext_vector_type(8))) short sh8;
typedef __attribute__((ext_vector_type(8))) unsigned short us8;
typedef unsigned short u16;

__device__ __forceinline__ u16 f2bf(float f) {
  __hip_bfloat16 h = __float2bfloat16(f);
  return __builtin_bit_cast(u16, h);
}

__device__ __forceinline__ float gelu_tanh(float x) {
  float u = 0.7978845608028654f * (x + 0.044715f * x * x * x);
  u = fminf(fmaxf(u, -15.f), 15.f);
  float ez = __expf(2.f * u);
  return 0.5f * x * (1.f + (ez - 1.f) / (ez + 1.f));
}

__device__ __forceinline__ void gload_lds16(const void* g, void* l) {
  __builtin_amdgcn_global_load_lds(
      (const __attribute__((address_space(1))) unsigned int*)g,
      (__attribute__((address_space(3))) unsigned int*)l, 16, 0, 0);
}

template <int N>
__device__ __forceinline__ void wait_vmcnt() {
  if constexpr (N == 0) asm volatile("s_waitcnt vmcnt(0)" ::: "memory");
  else if constexpr (N == 4) asm volatile("s_waitcnt vmcnt(4)" ::: "memory");
}

// ---------------- weight fp32 -> bf16 (both tensors, one full-BW pass) -------
__global__ __launch_bounds__(256) void wconv_kernel(
    const float* __restrict__ w1, const float* __restrict__ w2,
    u16* __restrict__ w1b, u16* __restrict__ w2b) {
  size_t i = ((size_t)blockIdx.x * 256 + threadIdx.x) * 8;
  fl4 a0 = *(const fl4*)(w1 + i);
  fl4 a1 = *(const fl4*)(w1 + i + 4);
  fl4 b0 = *(const fl4*)(w2 + i);
  fl4 b1 = *(const fl4*)(w2 + i + 4);
  us8 oa, ob;
#pragma unroll
  for (int j = 0; j < 4; j++) {
    oa[j] = f2bf(a0[j]); oa[j + 4] = f2bf(a1[j]);
    ob[j] = f2bf(b0[j]); ob[j + 4] = f2bf(b1[j]);
  }
  *(us8*)(w1b + i) = oa;
  *(us8*)(w2b + i) = ob;
}

// ---------------- router: logits + top-2 ----------------
__global__ __launch_bounds__(256) void router_kernel(
    const float* __restrict__ x, const float* __restrict__ rw,
    int* __restrict__ tok_e, float* __restrict__ tok_w, int* __restrict__ ctl) {
  int tid = threadIdx.x;
  int wv = tid >> 6, lane = tid & 63;
  int t = blockIdx.x * 4 + wv;
  if (t >= T_TOK) return;

  const float* xp = x + (size_t)t * DM + lane * 16;
  fl4 xq[4];
#pragma unroll
  for (int i = 0; i < 4; i++) xq[i] = *(const fl4*)(xp + i * 4);

  float acc8[NE];
#pragma unroll
  for (int e = 0; e < NE; e++) {
    const float* wp = rw + (size_t)e * DM + lane * 16;
    float s = 0.f;
#pragma unroll
    for (int i = 0; i < 4; i++) {
      fl4 w4 = *(const fl4*)(wp + i * 4);
      s += xq[i][0] * w4[0] + xq[i][1] * w4[1] + xq[i][2] * w4[2] + xq[i][3] * w4[3];
    }
    acc8[e] = s;
  }
#pragma unroll
  for (int e = 0; e < NE; e++) {
#pragma unroll
    for (int off = 32; off > 0; off >>= 1) acc8[e] += __shfl_xor(acc8[e], off);
  }
  if (lane == 0) {
    float v1 = -1e30f, v2 = -1e30f;
    int i1 = 0, i2 = 0;
#pragma unroll
    for (int e = 0; e < NE; e++) {
      float v = acc8[e];
      if (v > v1) { v2 = v1; i2 = i1; v1 = v; i1 = e; }
      else if (v > v2) { v2 = v; i2 = e; }
    }
    float ex = expf(v2 - v1);
    float s = 1.0f + ex;
    tok_e[t * 2] = i1; tok_e[t * 2 + 1] = i2;
    tok_w[t * 2] = 1.0f / s; tok_w[t * 2 + 1] = ex / s;
    atomicAdd(&ctl[i1], 1);
    atomicAdd(&ctl[i2], 1);
  }
}

// ctl: [0..7] counts, [8..15] cursors (padded), [16..23] padded bases,
// [24..31] compact bases, [32..103] tile_expert
__global__ __launch_bounds__(128) void scan_kernel(int* __restrict__ ctl) {
  __shared__ int base_s[NE], cbase_s[NE];
  __shared__ int tb_s[NE + 1];
  int tid = threadIdx.x;
  if (tid == 0) {
    int s = 0, cs = 0, tb = 0;
    for (int e = 0; e < NE; e++) {
      base_s[e] = s;
      cbase_s[e] = cs;
      tb_s[e] = tb;
      int c = ctl[e];
      int nte = (c + 127) >> 7;
      tb += nte;
      s += nte << 7;
      cs += c;
    }
    tb_s[NE] = tb;
  }
  __syncthreads();
  if (tid < NE) {
    ctl[16 + tid] = base_s[tid];
    ctl[8 + tid] = base_s[tid];
    ctl[24 + tid] = cbase_s[tid];
  }
  if (tid < MAXTILES) {
    int e = -1;
#pragma unroll
    for (int k = 0; k < NE; k++)
      if (tid >= tb_s[k] && tid < tb_s[k + 1]) e = k;
    ctl[32 + tid] = e;
  }
}

__global__ __launch_bounds__(256) void assign_kernel(
    const int* __restrict__ tok_e, int* __restrict__ ctl,
    int* __restrict__ tok_map_c, int* __restrict__ islot) {
  int t = blockIdx.x * 256 + threadIdx.x;
  if (t < T_TOK) {
#pragma unroll
    for (int k = 0; k < 2; k++) {
      int e = tok_e[t * 2 + k];
      int slot = atomicAdd(&ctl[8 + e], 1);
      int cslot = slot - ctl[16 + e] + ctl[24 + e];
      tok_map_c[cslot] = t;
      islot[t * 2 + k] = cslot;
    }
  }
}

// gather: xg[c] = bf16(x[tok_map_c[c]])
__global__ __launch_bounds__(256) void gather_kernel(
    const float* __restrict__ x, const int* __restrict__ tok_map_c,
    u16* __restrict__ xg) {
  int c = blockIdx.x * 2 + (threadIdx.x >> 7);
  int li = threadIdx.x & 127;
  int t = tok_map_c[c];
  const float* xp = x + (size_t)t * DM + li * 8;
  fl4 v0 = *(const fl4*)xp;
  fl4 v1 = *(const fl4*)(xp + 4);
  us8 o;
#pragma unroll
  for (int j = 0; j < 4; j++) { o[j] = f2bf(v0[j]); o[j + 4] = f2bf(v1[j]); }
  *(us8*)(xg + (size_t)c * DM + li * 8) = o;
}

// combine: out[t] = sum_k w_k * (y0[s_k] + y1[s_k] + b2[e_k])
__global__ __launch_bounds__(256) void combine_kernel(
    const float* __restrict__ y0, const float* __restrict__ y1,
    const float* __restrict__ b2, const int* __restrict__ tok_e,
    const int* __restrict__ islot, const float* __restrict__ tok_w,
    float* __restrict__ out) {
  int idx = blockIdx.x * 256 + threadIdx.x;
  int t = idx >> 8;
  int c4 = (idx & 255) * 4;
  int e0 = tok_e[t * 2], e1 = tok_e[t * 2 + 1];
  int s0 = islot[t * 2], s1 = islot[t * 2 + 1];
  float w0 = tok_w[t * 2], w1 = tok_w[t * 2 + 1];
  fl4 a0 = *(const fl4*)(y0 + (size_t)s0 * DM + c4);
  fl4 a1 = *(const fl4*)(y1 + (size_t)s0 * DM + c4);
  fl4 c0 = *(const fl4*)(y0 + (size_t)s1 * DM + c4);
  fl4 c1 = *(const fl4*)(y1 + (size_t)s1 * DM + c4);
  fl4 bb0 = *(const fl4*)(b2 + (size_t)e0 * DM + c4);
  fl4 bb1 = *(const fl4*)(b2 + (size_t)e1 * DM + c4);
  fl4 o;
#pragma unroll
  for (int i = 0; i < 4; i++)
    o[i] = w0 * (a0[i] + a1[i] + bb0[i]) + w1 * (c0[i] + c1[i] + bb1[i]);
  *(fl4*)(out + (size_t)t * DM + c4) = o;
}

// ---- grouped GEMM: 128x128, BK=32, 4 waves, r11 loop + LDS-repack epilogue --
// fc1: coalesced us8 H-stores via LDS repack (stride 136 u16).
// fc2: K-split partials -> y0/y1 NON-atomic, coalesced fl4 via LDS repack
//      (stride 68 f32, 2 column-halves).
template <bool FC1>
__global__ __launch_bounds__(256, 4) void moe_gemm(
    const u16* __restrict__ Ab, const u16* __restrict__ Wb,
    const float* __restrict__ bias, u16* __restrict__ Hout,
    float* __restrict__ Yout, const int* __restrict__ ctl) {
  constexpr int KTOT = FC1 ? DM : DH;
  constexpr int NTOT = FC1 ? DH : DM;
  constexpr int NKL = FC1 ? 32 : 64;

  __shared__ char SH[36864];  // 2x8KB As + 2x8KB Bs (loop); 34.8KB repack (epi)

  int bid = blockIdx.x;
  int x = bid & 7, idx = bid >> 3;
  int tl = idx % 9, pn = idx / 9;
  int nt, ks;
  if (FC1) { nt = pn; ks = 0; }
  else     { nt = pn >> 1; ks = pn & 1; }
  int tile = x * 9 + tl;

  int e = ctl[32 + tile];
  if (e < 0) return;
  int cnt = ctl[e], base = ctl[16 + e], cbase = ctl[24 + e];
  int hbase = cbase - base;
  int cmax = cbase + cnt - 1;
  int m0 = tile * 128;

  int tid = threadIdx.x;
  int wv = tid >> 6, lane = tid & 63;
  int wr = wv >> 1, wc = wv & 1;
  int khalf = lane >> 4, l15 = lane & 15;

  const u16* asrc[2];
  const u16* bsrc[2];
#pragma unroll
  for (int r2 = 0; r2 < 2; r2++) {
    int c = r2 * 256 + tid;
    int row = c >> 2, q = c & 3;
    int qs = q ^ ((row >> 2) & 3);
    int crow = m0 + row + hbase;
    if (crow > cmax) crow = cmax;
    asrc[r2] = Ab + (size_t)crow * KTOT + ks * 2048 + qs * 8;
    bsrc[r2] = Wb + ((size_t)e * NTOT + nt * 128 + row) * KTOT + ks * 2048 + qs * 8;
  }

#define STAGE(B, KT)                                                           \
  { _Pragma("unroll") for (int r2 = 0; r2 < 2; r2++) {                         \
      gload_lds16(asrc[r2] + (KT) * 32,                                        \
                  SH + (B) * 8192 + (r2 * 256 + wv * 64) * 16);                \
      gload_lds16(bsrc[r2] + (KT) * 32,                                        \
                  SH + 16384 + (B) * 8192 + (r2 * 256 + wv * 64) * 16);        \
    } }

  int aoff[4], boff[4];
#pragma unroll
  for (int m = 0; m < 4; m++) {
    int rowl = wr * 64 + m * 16 + l15;
    aoff[m] = rowl * 64 + ((khalf * 16) ^ ((rowl & 12) << 2));
  }
#pragma unroll
  for (int n = 0; n < 4; n++) {
    int coll = wc * 64 + n * 16 + l15;
    boff[n] = coll * 64 + ((khalf * 16) ^ ((coll & 12) << 2));
  }

  fl4 acc[4][4];
#pragma unroll
  for (int m = 0; m < 4; m++)
#pragma unroll
    for (int n = 0; n < 4; n++) acc[m][n] = (fl4){0.f, 0.f, 0.f, 0.f};

#define COMPUTE(B)                                                             \
  {                                                                            \
    sh8 af[4], bfr[4];                                                         \
    _Pragma("unroll") for (int m = 0; m < 4; m++)                              \
      af[m] = *(const sh8*)(SH + (B) * 8192 + aoff[m]);                        \
    _Pragma("unroll") for (int n = 0; n < 4; n++)                              \
      bfr[n] = *(const sh8*)(SH + 16384 + (B) * 8192 + boff[n]);               \
    __builtin_amdgcn_s_setprio(1);                                             \
    _Pragma("unroll") for (int m = 0; m < 4; m++)                              \
    _Pragma("unroll") for (int n = 0; n < 4; n++)                              \
      acc[m][n] = __builtin_amdgcn_mfma_f32_16x16x32_bf16(af[m], bfr[n],       \
                                                          acc[m][n], 0, 0, 0); \
    __builtin_amdgcn_s_setprio(0);                                             \
  }

  STAGE(0, 0);
  for (int kt = 0; kt < NKL; kt += 2) {
    STAGE(1, kt + 1);
    wait_vmcnt<4>();
    __builtin_amdgcn_s_barrier();
    COMPUTE(0);
    __builtin_amdgcn_s_barrier();
    if (kt + 2 < NKL) {
      STAGE(0, kt + 2);
      wait_vmcnt<4>();
    } else {
      wait_vmcnt<0>();
    }
    __builtin_amdgcn_s_barrier();
    COMPUTE(1);
    __builtin_amdgcn_s_barrier();
  }
  // After the final barrier all waves' LDS reads are complete -> SH reusable.

  if (FC1) {
    u16* t16 = (u16*)SH;
#pragma unroll
    for (int n = 0; n < 4; n++) {
      int col = wc * 64 + n * 16 + l15;
      float bn = bias[(size_t)e * DH + nt * 128 + col];
#pragma unroll
      for (int m = 0; m < 4; m++)
#pragma unroll
        for (int j = 0; j < 4; j++) {
          int row = wr * 64 + m * 16 + khalf * 4 + j;
          t16[row * 136 + col] = f2bf(gelu_tanh(acc[m][n][j] + bn));
        }
    }
    asm volatile("s_waitcnt lgkmcnt(0)" ::: "memory");
    __builtin_amdgcn_s_barrier();
#pragma unroll
    for (int p = 0; p < 8; p++) {
      int c = p * 256 + tid;          // 128 rows x 16 us8-chunks
      int row = c >> 4, ch = c & 15;
      int crow = m0 + row + hbase;
      if (crow <= cmax) {
        us8 v = *(const us8*)(t16 + row * 136 + ch * 8);
        *(us8*)(Hout + (size_t)crow * DH + nt * 128 + ch * 8) = v;
      }
    }
  } else {
    float* t32 = (float*)SH;
    float* Yp = Yout + (size_t)ks * NSLOT * DM;
#pragma unroll
    for (int h = 0; h < 2; h++) {
      if (wc == h) {
#pragma unroll
        for (int n = 0; n < 4; n++)
#pragma unroll
          for (int m = 0; m < 4; m++)
#pragma unroll
            for (int j = 0; j < 4; j++) {
              int row = wr * 64 + m * 16 + khalf * 4 + j;
              t32[row * 68 + n * 16 + l15] = acc[m][n][j];
            }
      }
      asm volatile("s_waitcnt lgkmcnt(0)" ::: "memory");
      __builtin_amdgcn_s_barrier();
#pragma unroll
      for (int p = 0; p < 8; p++) {
        int c = p * 256 + tid;        // 128 rows x 16 fl4-chunks (64 cols)
        int row = c >> 4, ch = c & 15;
        int crow = m0 + row + hbase;
        if (crow <= cmax) {
          fl4 v = *(const fl4*)(t32 + row * 68 + ch * 4);
          *(fl4*)(Yp + (size_t)crow * DM + nt * 128 + h * 64 + ch * 4) = v;
        }
      }
      if (h == 0) __builtin_amdgcn_s_barrier();
    }
  }
#undef STAGE
#undef COMPUTE
}

extern "C" void kernel_launch(void* const* d_in, const int* in_sizes, int n_in,
                              void* d_out, int out_size, void* d_ws, size_t ws_size,
                              hipStream_t stream) {
  const float* x  = (const float*)d_in[0];
  const float* rw = (const float*)d_in[1];
  const float* w1 = (const float*)d_in[2];
  const float* b1 = (const float*)d_in[3];
  const float* w2 = (const float*)d_in[4];
  const float* b2 = (const float*)d_in[5];
  float* out = (float*)d_out;

  char* ws = (char*)d_ws;
  size_t off = 0;
  u16* xg  = (u16*)(ws + off); off += (size_t)NSLOT * DM * 2;   // 16.8 MB
  u16* H   = (u16*)(ws + off); off += (size_t)NSLOT * DH * 2;   // 67.1 MB
  u16* w1b = (u16*)(ws + off); off += WELEMS * 2;               // 67.1 MB
  u16* w2b = (u16*)(ws + off); off += WELEMS * 2;               // 67.1 MB
  int* tok_map_c = (int*)(ws + off); off += (size_t)NSLOT * 4;
  int* tok_e     = (int*)(ws + off); off += (size_t)T_TOK * 8;
  float* tok_w   = (float*)(ws + off); off += (size_t)T_TOK * 8;
  int* islot     = (int*)(ws + off); off += (size_t)T_TOK * 8;
  int* ctl       = (int*)(ws + off); off += 512;
  // y0,y1 (compact fp32, 33.6 MB each = 67.1 MB) overlay w1b (dead after fc1)
  float* y0 = (float*)w1b;
  float* y1 = y0 + (size_t)NSLOT * DM;

  hipMemsetAsync(ctl, 0, 128 * 4, stream);

  router_kernel<<<T_TOK / 4, 256, 0, stream>>>(x, rw, tok_e, tok_w, ctl);
  scan_kernel<<<1, 128, 0, stream>>>(ctl);
  assign_kernel<<<T_TOK / 256, 256, 0, stream>>>(tok_e, ctl, tok_map_c, islot);
  gather_kernel<<<NSLOT / 2, 256, 0, stream>>>(x, tok_map_c, xg);
  wconv_kernel<<<WELEMS / (256 * 8), 256, 0, stream>>>(w1, w2, w1b, w2b);

  moe_gemm<true><<<8 * 9 * 32, 256, 0, stream>>>(xg, w1b, b1, H, nullptr, ctl);
  moe_gemm<false><<<8 * 9 * 16, 256, 0, stream>>>(H, w2b, nullptr, nullptr, y0, ctl);
  combine_kernel<<<T_TOK * DM / 4 / 256, 256, 0, stream>>>(
      y0, y1, b2, tok_e, islot, tok_w, out);
}

// Round 17
// 451.711 us; speedup vs baseline: 1.1795x; 1.0240x over previous
//
#include <hip/hip_runtime.h>
#include <hip/hip_bf16.h>

#define T_TOK 4096
#define DM 1024
#define DH 4096
#define NE 8
#define NSLOT (T_TOK * 2)            // compact slots: exactly sum(cnt)
#define MAXTILES 72
#define WELEMS ((size_t)NE * DH * DM)

typedef __attribute__((ext_vector_type(4))) float fl4;
typedef __attribute__((ext_vector_type(8))) short sh8;
typedef __attribute__((ext_vector_type(8))) unsigned short us8;
typedef unsigned short u16;

__device__ __forceinline__ u16 f2bf(float f) {
  __hip_bfloat16 h = __float2bfloat16(f);
  return __builtin_bit_cast(u16, h);
}

__device__ __forceinline__ float gelu_tanh(float x) {
  float u = 0.7978845608028654f * (x + 0.044715f * x * x * x);
  u = fminf(fmaxf(u, -15.f), 15.f);
  float ez = __expf(2.f * u);
  return 0.5f * x * (1.f + (ez - 1.f) / (ez + 1.f));
}

__device__ __forceinline__ void gload_lds16(const void* g, void* l) {
  __builtin_amdgcn_global_load_lds(
      (const __attribute__((address_space(1))) unsigned int*)g,
      (__attribute__((address_space(3))) unsigned int*)l, 16, 0, 0);
}

template <int N>
__device__ __forceinline__ void wait_vmcnt() {
  if constexpr (N == 0) asm volatile("s_waitcnt vmcnt(0)" ::: "memory");
  else if constexpr (N == 4) asm volatile("s_waitcnt vmcnt(4)" ::: "memory");
}

// ---------------- weight fp32 -> bf16 (single tensor: w1) ----------------
__global__ __launch_bounds__(256) void wconv_kernel(
    const float* __restrict__ w, u16* __restrict__ wb) {
  size_t i = ((size_t)blockIdx.x * 256 + threadIdx.x) * 8;  // grid covers WELEMS
  fl4 a0 = *(const fl4*)(w + i);
  fl4 a1 = *(const fl4*)(w + i + 4);
  us8 oa;
#pragma unroll
  for (int j = 0; j < 4; j++) { oa[j] = f2bf(a0[j]); oa[j + 4] = f2bf(a1[j]); }
  *(us8*)(wb + i) = oa;
}

// ---------------- router: logits + top-2 ----------------
__global__ __launch_bounds__(256) void router_kernel(
    const float* __restrict__ x, const float* __restrict__ rw,
    int* __restrict__ tok_e, float* __restrict__ tok_w, int* __restrict__ ctl) {
  int tid = threadIdx.x;
  int wv = tid >> 6, lane = tid & 63;
  int t = blockIdx.x * 4 + wv;
  if (t >= T_TOK) return;

  const float* xp = x + (size_t)t * DM + lane * 16;
  fl4 xq[4];
#pragma unroll
  for (int i = 0; i < 4; i++) xq[i] = *(const fl4*)(xp + i * 4);

  float acc8[NE];
#pragma unroll
  for (int e = 0; e < NE; e++) {
    const float* wp = rw + (size_t)e * DM + lane * 16;
    float s = 0.f;
#pragma unroll
    for (int i = 0; i < 4; i++) {
      fl4 w4 = *(const fl4*)(wp + i * 4);
      s += xq[i][0] * w4[0] + xq[i][1] * w4[1] + xq[i][2] * w4[2] + xq[i][3] * w4[3];
    }
    acc8[e] = s;
  }
#pragma unroll
  for (int e = 0; e < NE; e++) {
#pragma unroll
    for (int off = 32; off > 0; off >>= 1) acc8[e] += __shfl_xor(acc8[e], off);
  }
  if (lane == 0) {
    float v1 = -1e30f, v2 = -1e30f;
    int i1 = 0, i2 = 0;
#pragma unroll
    for (int e = 0; e < NE; e++) {
      float v = acc8[e];
      if (v > v1) { v2 = v1; i2 = i1; v1 = v; i1 = e; }
      else if (v > v2) { v2 = v; i2 = e; }
    }
    float ex = expf(v2 - v1);
    float s = 1.0f + ex;
    tok_e[t * 2] = i1; tok_e[t * 2 + 1] = i2;
    tok_w[t * 2] = 1.0f / s; tok_w[t * 2 + 1] = ex / s;
    atomicAdd(&ctl[i1], 1);
    atomicAdd(&ctl[i2], 1);
  }
}

// ctl: [0..7] counts, [8..15] cursors (padded), [16..23] padded bases,
// [24..31] compact bases, [32..103] tile_expert
__global__ __launch_bounds__(128) void scan_kernel(int* __restrict__ ctl) {
  __shared__ int base_s[NE], cbase_s[NE];
  __shared__ int tb_s[NE + 1];
  int tid = threadIdx.x;
  if (tid == 0) {
    int s = 0, cs = 0, tb = 0;
    for (int e = 0; e < NE; e++) {
      base_s[e] = s;
      cbase_s[e] = cs;
      tb_s[e] = tb;
      int c = ctl[e];
      int nte = (c + 127) >> 7;
      tb += nte;
      s += nte << 7;
      cs += c;
    }
    tb_s[NE] = tb;
  }
  __syncthreads();
  if (tid < NE) {
    ctl[16 + tid] = base_s[tid];
    ctl[8 + tid] = base_s[tid];
    ctl[24 + tid] = cbase_s[tid];
  }
  if (tid < MAXTILES) {
    int e = -1;
#pragma unroll
    for (int k = 0; k < NE; k++)
      if (tid >= tb_s[k] && tid < tb_s[k + 1]) e = k;
    ctl[32 + tid] = e;
  }
}

__global__ __launch_bounds__(256) void assign_kernel(
    const int* __restrict__ tok_e, int* __restrict__ ctl,
    int* __restrict__ tok_map_c, int* __restrict__ islot) {
  int t = blockIdx.x * 256 + threadIdx.x;
  if (t < T_TOK) {
#pragma unroll
    for (int k = 0; k < 2; k++) {
      int e = tok_e[t * 2 + k];
      int slot = atomicAdd(&ctl[8 + e], 1);
      int cslot = slot - ctl[16 + e] + ctl[24 + e];
      tok_map_c[cslot] = t;
      islot[t * 2 + k] = cslot;
    }
  }
}

// gather: xg[c] = bf16(x[tok_map_c[c]])
__global__ __launch_bounds__(256) void gather_kernel(
    const float* __restrict__ x, const int* __restrict__ tok_map_c,
    u16* __restrict__ xg) {
  int c = blockIdx.x * 2 + (threadIdx.x >> 7);
  int li = threadIdx.x & 127;
  int t = tok_map_c[c];
  const float* xp = x + (size_t)t * DM + li * 8;
  fl4 v0 = *(const fl4*)xp;
  fl4 v1 = *(const fl4*)(xp + 4);
  us8 o;
#pragma unroll
  for (int j = 0; j < 4; j++) { o[j] = f2bf(v0[j]); o[j + 4] = f2bf(v1[j]); }
  *(us8*)(xg + (size_t)c * DM + li * 8) = o;
}

// combine: out[t] = sum_k w_k * (y0[s_k] + y1[s_k] + b2[e_k])
__global__ __launch_bounds__(256) void combine_kernel(
    const float* __restrict__ y0, const float* __restrict__ y1,
    const float* __restrict__ b2, const int* __restrict__ tok_e,
    const int* __restrict__ islot, const float* __restrict__ tok_w,
    float* __restrict__ out) {
  int idx = blockIdx.x * 256 + threadIdx.x;
  int t = idx >> 8;
  int c4 = (idx & 255) * 4;
  int e0 = tok_e[t * 2], e1 = tok_e[t * 2 + 1];
  int s0 = islot[t * 2], s1 = islot[t * 2 + 1];
  float w0 = tok_w[t * 2], w1 = tok_w[t * 2 + 1];
  fl4 a0 = *(const fl4*)(y0 + (size_t)s0 * DM + c4);
  fl4 a1 = *(const fl4*)(y1 + (size_t)s0 * DM + c4);
  fl4 c0 = *(const fl4*)(y0 + (size_t)s1 * DM + c4);
  fl4 c1 = *(const fl4*)(y1 + (size_t)s1 * DM + c4);
  fl4 bb0 = *(const fl4*)(b2 + (size_t)e0 * DM + c4);
  fl4 bb1 = *(const fl4*)(b2 + (size_t)e1 * DM + c4);
  fl4 o;
#pragma unroll
  for (int i = 0; i < 4; i++)
    o[i] = w0 * (a0[i] + a1[i] + bb0[i]) + w1 * (c0[i] + c1[i] + bb1[i]);
  *(fl4*)(out + (size_t)t * DM + c4) = o;
}

// ---- grouped GEMM: 128x128, BK=32, 4 waves, r16 loop + LDS-repack epilogue --
// FC1 additionally carries w2-conversion FILLER BLOCKS (every 4th group of 8):
// they consume fc1's spare HBM bandwidth (~4.4 TB/s) + idle slots instead of a
// serial 67us wconv pass. XCD mapping preserved: conv test uses bid>>3 so
// bid&7 == hw XCD for GEMM blocks.
template <bool FC1>
__global__ __launch_bounds__(256, 4) void moe_gemm(
    const u16* __restrict__ Ab, const u16* __restrict__ Wb,
    const float* __restrict__ bias, u16* __restrict__ Hout,
    float* __restrict__ Yout, const int* __restrict__ ctl,
    const float* __restrict__ cw_src, u16* __restrict__ cw_dst) {
  constexpr int KTOT = FC1 ? DM : DH;
  constexpr int NTOT = FC1 ? DH : DM;
  constexpr int NKL = FC1 ? 32 : 64;

  __shared__ char SH[36864];

  int bid = blockIdx.x;
  int tid = threadIdx.x;
  int g;
  if (FC1) {
    int gg = bid >> 3;
    if ((gg & 3) == 3) {
      // ---- w2 conversion filler block (cb in [0,768)) ----
      int cb = (gg >> 2) * 8 + (bid & 7);
      size_t stride = (size_t)768 * 256 * 8;
      for (size_t i = ((size_t)cb * 256 + tid) * 8; i < WELEMS; i += stride) {
        fl4 a0 = *(const fl4*)(cw_src + i);
        fl4 a1 = *(const fl4*)(cw_src + i + 4);
        us8 oa;
#pragma unroll
        for (int j = 0; j < 4; j++) { oa[j] = f2bf(a0[j]); oa[j + 4] = f2bf(a1[j]); }
        *(us8*)(cw_dst + i) = oa;
      }
      return;
    }
    g = ((gg >> 2) * 3 + (gg & 3)) * 8 + (bid & 7);
  } else {
    g = bid;
  }

  int x = g & 7, idx = g >> 3;
  int tl = idx % 9, pn = idx / 9;
  int nt, ks;
  if (FC1) { nt = pn; ks = 0; }
  else     { nt = pn >> 1; ks = pn & 1; }
  int tile = x * 9 + tl;

  int e = ctl[32 + tile];
  if (e < 0) return;
  int cnt = ctl[e], base = ctl[16 + e], cbase = ctl[24 + e];
  int hbase = cbase - base;
  int cmax = cbase + cnt - 1;
  int m0 = tile * 128;

  int wv = tid >> 6, lane = tid & 63;
  int wr = wv >> 1, wc = wv & 1;
  int khalf = lane >> 4, l15 = lane & 15;

  const u16* asrc[2];
  const u16* bsrc[2];
#pragma unroll
  for (int r2 = 0; r2 < 2; r2++) {
    int c = r2 * 256 + tid;
    int row = c >> 2, q = c & 3;
    int qs = q ^ ((row >> 2) & 3);
    int crow = m0 + row + hbase;
    if (crow > cmax) crow = cmax;
    asrc[r2] = Ab + (size_t)crow * KTOT + ks * 2048 + qs * 8;
    bsrc[r2] = Wb + ((size_t)e * NTOT + nt * 128 + row) * KTOT + ks * 2048 + qs * 8;
  }

#define STAGE(B, KT)                                                           \
  { _Pragma("unroll") for (int r2 = 0; r2 < 2; r2++) {                         \
      gload_lds16(asrc[r2] + (KT) * 32,                                        \
                  SH + (B) * 8192 + (r2 * 256 + wv * 64) * 16);                \
      gload_lds16(bsrc[r2] + (KT) * 32,                                        \
                  SH + 16384 + (B) * 8192 + (r2 * 256 + wv * 64) * 16);        \
    } }

  int aoff[4], boff[4];
#pragma unroll
  for (int m = 0; m < 4; m++) {
    int rowl = wr * 64 + m * 16 + l15;
    aoff[m] = rowl * 64 + ((khalf * 16) ^ ((rowl & 12) << 2));
  }
#pragma unroll
  for (int n = 0; n < 4; n++) {
    int coll = wc * 64 + n * 16 + l15;
    boff[n] = coll * 64 + ((khalf * 16) ^ ((coll & 12) << 2));
  }

  fl4 acc[4][4];
#pragma unroll
  for (int m = 0; m < 4; m++)
#pragma unroll
    for (int n = 0; n < 4; n++) acc[m][n] = (fl4){0.f, 0.f, 0.f, 0.f};

#define COMPUTE(B)                                                             \
  {                                                                            \
    sh8 af[4], bfr[4];                                                         \
    _Pragma("unroll") for (int m = 0; m < 4; m++)                              \
      af[m] = *(const sh8*)(SH + (B) * 8192 + aoff[m]);                        \
    _Pragma("unroll") for (int n = 0; n < 4; n++)                              \
      bfr[n] = *(const sh8*)(SH + 16384 + (B) * 8192 + boff[n]);               \
    __builtin_amdgcn_s_setprio(1);                                             \
    _Pragma("unroll") for (int m = 0; m < 4; m++)                              \
    _Pragma("unroll") for (int n = 0; n < 4; n++)                              \
      acc[m][n] = __builtin_amdgcn_mfma_f32_16x16x32_bf16(af[m], bfr[n],       \
                                                          acc[m][n], 0, 0, 0); \
    __builtin_amdgcn_s_setprio(0);                                             \
  }

  STAGE(0, 0);
  for (int kt = 0; kt < NKL; kt += 2) {
    STAGE(1, kt + 1);
    wait_vmcnt<4>();
    __builtin_amdgcn_s_barrier();
    COMPUTE(0);
    __builtin_amdgcn_s_barrier();
    if (kt + 2 < NKL) {
      STAGE(0, kt + 2);
      wait_vmcnt<4>();
    } else {
      wait_vmcnt<0>();
    }
    __builtin_amdgcn_s_barrier();
    COMPUTE(1);
    __builtin_amdgcn_s_barrier();
  }
  // After the final barrier all waves' LDS reads are complete -> SH reusable.

  if (FC1) {
    u16* t16 = (u16*)SH;
#pragma unroll
    for (int n = 0; n < 4; n++) {
      int col = wc * 64 + n * 16 + l15;
      float bn = bias[(size_t)e * DH + nt * 128 + col];
#pragma unroll
      for (int m = 0; m < 4; m++)
#pragma unroll
        for (int j = 0; j < 4; j++) {
          int row = wr * 64 + m * 16 + khalf * 4 + j;
          t16[row * 136 + col] = f2bf(gelu_tanh(acc[m][n][j] + bn));
        }
    }
    asm volatile("s_waitcnt lgkmcnt(0)" ::: "memory");
    __builtin_amdgcn_s_barrier();
#pragma unroll
    for (int p = 0; p < 8; p++) {
      int c = p * 256 + tid;          // 128 rows x 16 us8-chunks
      int row = c >> 4, ch = c & 15;
      int crow = m0 + row + hbase;
      if (crow <= cmax) {
        us8 v = *(const us8*)(t16 + row * 136 + ch * 8);
        *(us8*)(Hout + (size_t)crow * DH + nt * 128 + ch * 8) = v;
      }
    }
  } else {
    float* t32 = (float*)SH;
    float* Yp = Yout + (size_t)ks * NSLOT * DM;
#pragma unroll
    for (int h = 0; h < 2; h++) {
      if (wc == h) {
#pragma unroll
        for (int n = 0; n < 4; n++)
#pragma unroll
          for (int m = 0; m < 4; m++)
#pragma unroll
            for (int j = 0; j < 4; j++) {
              int row = wr * 64 + m * 16 + khalf * 4 + j;
              t32[row * 68 + n * 16 + l15] = acc[m][n][j];
            }
      }
      asm volatile("s_waitcnt lgkmcnt(0)" ::: "memory");
      __builtin_amdgcn_s_barrier();
#pragma unroll
      for (int p = 0; p < 8; p++) {
        int c = p * 256 + tid;        // 128 rows x 16 fl4-chunks (64 cols)
        int row = c >> 4, ch = c & 15;
        int crow = m0 + row + hbase;
        if (crow <= cmax) {
          fl4 v = *(const fl4*)(t32 + row * 68 + ch * 4);
          *(fl4*)(Yp + (size_t)crow * DM + nt * 128 + h * 64 + ch * 4) = v;
        }
      }
      if (h == 0) __builtin_amdgcn_s_barrier();
    }
  }
#undef STAGE
#undef COMPUTE
}

extern "C" void kernel_launch(void* const* d_in, const int* in_sizes, int n_in,
                              void* d_out, int out_size, void* d_ws, size_t ws_size,
                              hipStream_t stream) {
  const float* x  = (const float*)d_in[0];
  const float* rw = (const float*)d_in[1];
  const float* w1 = (const float*)d_in[2];
  const float* b1 = (const float*)d_in[3];
  const float* w2 = (const float*)d_in[4];
  const float* b2 = (const float*)d_in[5];
  float* out = (float*)d_out;

  char* ws = (char*)d_ws;
  size_t off = 0;
  u16* xg  = (u16*)(ws + off); off += (size_t)NSLOT * DM * 2;   // 16.8 MB
  u16* H   = (u16*)(ws + off); off += (size_t)NSLOT * DH * 2;   // 67.1 MB
  u16* w1b = (u16*)(ws + off); off += WELEMS * 2;               // 67.1 MB
  u16* w2b = (u16*)(ws + off); off += WELEMS * 2;               // 67.1 MB
  int* tok_map_c = (int*)(ws + off); off += (size_t)NSLOT * 4;
  int* tok_e     = (int*)(ws + off); off += (size_t)T_TOK * 8;
  float* tok_w   = (float*)(ws + off); off += (size_t)T_TOK * 8;
  int* islot     = (int*)(ws + off); off += (size_t)T_TOK * 8;
  int* ctl       = (int*)(ws + off); off += 512;
  // y0,y1 (compact fp32, 33.6 MB each) overlay w1b (dead after fc1)
  float* y0 = (float*)w1b;
  float* y1 = y0 + (size_t)NSLOT * DM;

  hipMemsetAsync(ctl, 0, 128 * 4, stream);

  router_kernel<<<T_TOK / 4, 256, 0, stream>>>(x, rw, tok_e, tok_w, ctl);
  scan_kernel<<<1, 128, 0, stream>>>(ctl);
  assign_kernel<<<T_TOK / 256, 256, 0, stream>>>(tok_e, ctl, tok_map_c, islot);
  gather_kernel<<<NSLOT / 2, 256, 0, stream>>>(x, tok_map_c, xg);
  wconv_kernel<<<WELEMS / (256 * 8), 256, 0, stream>>>(w1, w1b);

  // fc1 + fused w2 conversion: 2304 GEMM groups + 768 conv blocks = 3072
  moe_gemm<true><<<3072, 256, 0, stream>>>(
      xg, w1b, b1, H, nullptr, ctl, w2, w2b);
  moe_gemm<false><<<8 * 9 * 16, 256, 0, stream>>>(
      H, w2b, nullptr, nullptr, y0, ctl, nullptr, nullptr);
  combine_kernel<<<T_TOK * DM / 4 / 256, 256, 0, stream>>>(
      y0, y1, b2, tok_e, islot, tok_w, out);
}

// Round 18
// 322.656 us; speedup vs baseline: 1.6513x; 1.4000x over previous
//
#include <hip/hip_runtime.h>
#include <hip/hip_bf16.h>

#define T_TOK 4096
#define DM 1024
#define DH 4096
#define NE 8
#define NSLOT (T_TOK * 2)            // compact slots: exactly sum(cnt)
#define MAXTILES 72
#define WELEMS ((size_t)NE * DH * DM)
#define CONVB 768                    // conv filler blocks in router kernel

typedef __attribute__((ext_vector_type(4))) float fl4;
typedef __attribute__((ext_vector_type(8))) short sh8;
typedef __attribute__((ext_vector_type(8))) unsigned short us8;
typedef unsigned short u16;

__device__ __forceinline__ u16 f2bf(float f) {
  __hip_bfloat16 h = __float2bfloat16(f);
  return __builtin_bit_cast(u16, h);
}

__device__ __forceinline__ float gelu_tanh(float x) {
  float u = 0.7978845608028654f * (x + 0.044715f * x * x * x);
  u = fminf(fmaxf(u, -15.f), 15.f);
  float ez = __expf(2.f * u);
  return 0.5f * x * (1.f + (ez - 1.f) / (ez + 1.f));
}

__device__ __forceinline__ void gload_lds16(const void* g, void* l) {
  __builtin_amdgcn_global_load_lds(
      (const __attribute__((address_space(1))) unsigned int*)g,
      (__attribute__((address_space(3))) unsigned int*)l, 16, 0, 0);
}

template <int N>
__device__ __forceinline__ void wait_vmcnt() {
  if constexpr (N == 0) asm volatile("s_waitcnt vmcnt(0)" ::: "memory");
  else if constexpr (N == 4) asm volatile("s_waitcnt vmcnt(4)" ::: "memory");
}

// ---------------- router + w1 conversion filler ----------------
// blocks [0,CONVB): w1 fp32->bf16 grid-stride; blocks [CONVB, CONVB+1024):
// router for 4 tokens each. No ctl writes (scanassign rebuilds counts).
__global__ __launch_bounds__(256) void router_conv_kernel(
    const float* __restrict__ x, const float* __restrict__ rw,
    int* __restrict__ tok_e, float* __restrict__ tok_w,
    const float* __restrict__ w1, u16* __restrict__ w1b) {
  int bid = blockIdx.x;
  int tid = threadIdx.x;
  if (bid < CONVB) {
    size_t stride = (size_t)CONVB * 256 * 8;
    for (size_t i = ((size_t)bid * 256 + tid) * 8; i < WELEMS; i += stride) {
      fl4 a0 = *(const fl4*)(w1 + i);
      fl4 a1 = *(const fl4*)(w1 + i + 4);
      us8 oa;
#pragma unroll
      for (int j = 0; j < 4; j++) { oa[j] = f2bf(a0[j]); oa[j + 4] = f2bf(a1[j]); }
      *(us8*)(w1b + i) = oa;
    }
    return;
  }
  int wv = tid >> 6, lane = tid & 63;
  int t = (bid - CONVB) * 4 + wv;
  if (t >= T_TOK) return;

  const float* xp = x + (size_t)t * DM + lane * 16;
  fl4 xq[4];
#pragma unroll
  for (int i = 0; i < 4; i++) xq[i] = *(const fl4*)(xp + i * 4);

  float acc8[NE];
#pragma unroll
  for (int e = 0; e < NE; e++) {
    const float* wp = rw + (size_t)e * DM + lane * 16;
    float s = 0.f;
#pragma unroll
    for (int i = 0; i < 4; i++) {
      fl4 w4 = *(const fl4*)(wp + i * 4);
      s += xq[i][0] * w4[0] + xq[i][1] * w4[1] + xq[i][2] * w4[2] + xq[i][3] * w4[3];
    }
    acc8[e] = s;
  }
#pragma unroll
  for (int e = 0; e < NE; e++) {
#pragma unroll
    for (int off = 32; off > 0; off >>= 1) acc8[e] += __shfl_xor(acc8[e], off);
  }
  if (lane == 0) {
    float v1 = -1e30f, v2 = -1e30f;
    int i1 = 0, i2 = 0;
#pragma unroll
    for (int e = 0; e < NE; e++) {
      float v = acc8[e];
      if (v > v1) { v2 = v1; i2 = i1; v1 = v; i1 = e; }
      else if (v > v2) { v2 = v; i2 = e; }
    }
    float ex = expf(v2 - v1);
    float s = 1.0f + ex;
    tok_e[t * 2] = i1; tok_e[t * 2 + 1] = i2;
    tok_w[t * 2] = 1.0f / s; tok_w[t * 2 + 1] = ex / s;
  }
}

// ---------------- scanassign (1 block x 1024): histogram + scan + assign -----
// ctl: [0..7] counts, [16..23] padded bases, [24..31] compact bases,
// [32..103] tile_expert. No pre-zeroing needed (histogram built in LDS).
__global__ __launch_bounds__(1024) void scanassign_kernel(
    const int* __restrict__ tok_e, int* __restrict__ ctl,
    int* __restrict__ tok_map_c, int* __restrict__ islot) {
  __shared__ int cnt_s[NE], cur_s[NE];
  __shared__ int base_s[NE], cbase_s[NE], tb_s[NE + 1];
  int tid = threadIdx.x;
  if (tid < NE) cnt_s[tid] = 0;
  __syncthreads();
  for (int i = tid; i < T_TOK * 2; i += 1024)
    atomicAdd(&cnt_s[tok_e[i]], 1);
  __syncthreads();
  if (tid == 0) {
    int s = 0, cs = 0, tb = 0;
    for (int e = 0; e < NE; e++) {
      base_s[e] = s;
      cbase_s[e] = cs;
      tb_s[e] = tb;
      int c = cnt_s[e];
      int nte = (c + 127) >> 7;
      tb += nte;
      s += nte << 7;
      cs += c;
    }
    tb_s[NE] = tb;
  }
  __syncthreads();
  if (tid < NE) {
    ctl[tid] = cnt_s[tid];
    ctl[16 + tid] = base_s[tid];
    ctl[24 + tid] = cbase_s[tid];
    cur_s[tid] = cbase_s[tid];
  }
  if (tid >= 32 && tid < 32 + MAXTILES) {
    int tt = tid - 32;
    int e = -1;
#pragma unroll
    for (int k = 0; k < NE; k++)
      if (tt >= tb_s[k] && tt < tb_s[k + 1]) e = k;
    ctl[32 + tt] = e;
  }
  __syncthreads();
  for (int t = tid; t < T_TOK; t += 1024) {
#pragma unroll
    for (int k = 0; k < 2; k++) {
      int e = tok_e[t * 2 + k];
      int c = atomicAdd(&cur_s[e], 1);
      tok_map_c[c] = t;
      islot[t * 2 + k] = c;
    }
  }
}

// gather: xg[c] = bf16(x[tok_map_c[c]])
__global__ __launch_bounds__(256) void gather_kernel(
    const float* __restrict__ x, const int* __restrict__ tok_map_c,
    u16* __restrict__ xg) {
  int c = blockIdx.x * 2 + (threadIdx.x >> 7);
  int li = threadIdx.x & 127;
  int t = tok_map_c[c];
  const float* xp = x + (size_t)t * DM + li * 8;
  fl4 v0 = *(const fl4*)xp;
  fl4 v1 = *(const fl4*)(xp + 4);
  us8 o;
#pragma unroll
  for (int j = 0; j < 4; j++) { o[j] = f2bf(v0[j]); o[j + 4] = f2bf(v1[j]); }
  *(us8*)(xg + (size_t)c * DM + li * 8) = o;
}

// combine: out[t] = sum_k w_k * (y0[s_k] + y1[s_k] + b2[e_k])
__global__ __launch_bounds__(256) void combine_kernel(
    const float* __restrict__ y0, const float* __restrict__ y1,
    const float* __restrict__ b2, const int* __restrict__ tok_e,
    const int* __restrict__ islot, const float* __restrict__ tok_w,
    float* __restrict__ out) {
  int idx = blockIdx.x * 256 + threadIdx.x;
  int t = idx >> 8;
  int c4 = (idx & 255) * 4;
  int e0 = tok_e[t * 2], e1 = tok_e[t * 2 + 1];
  int s0 = islot[t * 2], s1 = islot[t * 2 + 1];
  float w0 = tok_w[t * 2], w1 = tok_w[t * 2 + 1];
  fl4 a0 = *(const fl4*)(y0 + (size_t)s0 * DM + c4);
  fl4 a1 = *(const fl4*)(y1 + (size_t)s0 * DM + c4);
  fl4 c0 = *(const fl4*)(y0 + (size_t)s1 * DM + c4);
  fl4 c1 = *(const fl4*)(y1 + (size_t)s1 * DM + c4);
  fl4 bb0 = *(const fl4*)(b2 + (size_t)e0 * DM + c4);
  fl4 bb1 = *(const fl4*)(b2 + (size_t)e1 * DM + c4);
  fl4 o;
#pragma unroll
  for (int i = 0; i < 4; i++)
    o[i] = w0 * (a0[i] + a1[i] + bb0[i]) + w1 * (c0[i] + c1[i] + bb1[i]);
  *(fl4*)(out + (size_t)t * DM + c4) = o;
}

// ---- grouped GEMM: 128x128, BK=32, 4 waves, counted-vmcnt dbuf loop +
// LDS-repack epilogue. FC1 carries w2-conversion filler blocks.
template <bool FC1>
__global__ __launch_bounds__(256, 4) void moe_gemm(
    const u16* __restrict__ Ab, const u16* __restrict__ Wb,
    const float* __restrict__ bias, u16* __restrict__ Hout,
    float* __restrict__ Yout, const int* __restrict__ ctl,
    const float* __restrict__ cw_src, u16* __restrict__ cw_dst) {
  constexpr int KTOT = FC1 ? DM : DH;
  constexpr int NTOT = FC1 ? DH : DM;
  constexpr int NKL = FC1 ? 32 : 64;

  __shared__ char SH[36864];

  int bid = blockIdx.x;
  int tid = threadIdx.x;
  int g;
  if (FC1) {
    int gg = bid >> 3;
    if ((gg & 3) == 3) {
      int cb = (gg >> 2) * 8 + (bid & 7);
      size_t stride = (size_t)768 * 256 * 8;
      for (size_t i = ((size_t)cb * 256 + tid) * 8; i < WELEMS; i += stride) {
        fl4 a0 = *(const fl4*)(cw_src + i);
        fl4 a1 = *(const fl4*)(cw_src + i + 4);
        us8 oa;
#pragma unroll
        for (int j = 0; j < 4; j++) { oa[j] = f2bf(a0[j]); oa[j + 4] = f2bf(a1[j]); }
        *(us8*)(cw_dst + i) = oa;
      }
      return;
    }
    g = ((gg >> 2) * 3 + (gg & 3)) * 8 + (bid & 7);
  } else {
    g = bid;
  }

  int x = g & 7, idx = g >> 3;
  int tl = idx % 9, pn = idx / 9;
  int nt, ks;
  if (FC1) { nt = pn; ks = 0; }
  else     { nt = pn >> 1; ks = pn & 1; }
  int tile = x * 9 + tl;

  int e = ctl[32 + tile];
  if (e < 0) return;
  int cnt = ctl[e], base = ctl[16 + e], cbase = ctl[24 + e];
  int hbase = cbase - base;
  int cmax = cbase + cnt - 1;
  int m0 = tile * 128;

  int wv = tid >> 6, lane = tid & 63;
  int wr = wv >> 1, wc = wv & 1;
  int khalf = lane >> 4, l15 = lane & 15;

  const u16* asrc[2];
  const u16* bsrc[2];
#pragma unroll
  for (int r2 = 0; r2 < 2; r2++) {
    int c = r2 * 256 + tid;
    int row = c >> 2, q = c & 3;
    int qs = q ^ ((row >> 2) & 3);
    int crow = m0 + row + hbase;
    if (crow > cmax) crow = cmax;
    asrc[r2] = Ab + (size_t)crow * KTOT + ks * 2048 + qs * 8;
    bsrc[r2] = Wb + ((size_t)e * NTOT + nt * 128 + row) * KTOT + ks * 2048 + qs * 8;
  }

#define STAGE(B, KT)                                                           \
  { _Pragma("unroll") for (int r2 = 0; r2 < 2; r2++) {                         \
      gload_lds16(asrc[r2] + (KT) * 32,                                        \
                  SH + (B) * 8192 + (r2 * 256 + wv * 64) * 16);                \
      gload_lds16(bsrc[r2] + (KT) * 32,                                        \
                  SH + 16384 + (B) * 8192 + (r2 * 256 + wv * 64) * 16);        \
    } }

  int aoff[4], boff[4];
#pragma unroll
  for (int m = 0; m < 4; m++) {
    int rowl = wr * 64 + m * 16 + l15;
    aoff[m] = rowl * 64 + ((khalf * 16) ^ ((rowl & 12) << 2));
  }
#pragma unroll
  for (int n = 0; n < 4; n++) {
    int coll = wc * 64 + n * 16 + l15;
    boff[n] = coll * 64 + ((khalf * 16) ^ ((coll & 12) << 2));
  }

  fl4 acc[4][4];
#pragma unroll
  for (int m = 0; m < 4; m++)
#pragma unroll
    for (int n = 0; n < 4; n++) acc[m][n] = (fl4){0.f, 0.f, 0.f, 0.f};

#define COMPUTE(B)                                                             \
  {                                                                            \
    sh8 af[4], bfr[4];                                                         \
    _Pragma("unroll") for (int m = 0; m < 4; m++)                              \
      af[m] = *(const sh8*)(SH + (B) * 8192 + aoff[m]);                        \
    _Pragma("unroll") for (int n = 0; n < 4; n++)                              \
      bfr[n] = *(const sh8*)(SH + 16384 + (B) * 8192 + boff[n]);               \
    __builtin_amdgcn_s_setprio(1);                                             \
    _Pragma("unroll") for (int m = 0; m < 4; m++)                              \
    _Pragma("unroll") for (int n = 0; n < 4; n++)                              \
      acc[m][n] = __builtin_amdgcn_mfma_f32_16x16x32_bf16(af[m], bfr[n],       \
                                                          acc[m][n], 0, 0, 0); \
    __builtin_amdgcn_s_setprio(0);                                             \
  }

  STAGE(0, 0);
  for (int kt = 0; kt < NKL; kt += 2) {
    STAGE(1, kt + 1);
    wait_vmcnt<4>();
    __builtin_amdgcn_s_barrier();
    COMPUTE(0);
    __builtin_amdgcn_s_barrier();
    if (kt + 2 < NKL) {
      STAGE(0, kt + 2);
      wait_vmcnt<4>();
    } else {
      wait_vmcnt<0>();
    }
    __builtin_amdgcn_s_barrier();
    COMPUTE(1);
    __builtin_amdgcn_s_barrier();
  }

  if (FC1) {
    u16* t16 = (u16*)SH;
#pragma unroll
    for (int n = 0; n < 4; n++) {
      int col = wc * 64 + n * 16 + l15;
      float bn = bias[(size_t)e * DH + nt * 128 + col];
#pragma unroll
      for (int m = 0; m < 4; m++)
#pragma unroll
        for (int j = 0; j < 4; j++) {
          int row = wr * 64 + m * 16 + khalf * 4 + j;
          t16[row * 136 + col] = f2bf(gelu_tanh(acc[m][n][j] + bn));
        }
    }
    asm volatile("s_waitcnt lgkmcnt(0)" ::: "memory");
    __builtin_amdgcn_s_barrier();
#pragma unroll
    for (int p = 0; p < 8; p++) {
      int c = p * 256 + tid;
      int row = c >> 4, ch = c & 15;
      int crow = m0 + row + hbase;
      if (crow <= cmax) {
        us8 v = *(const us8*)(t16 + row * 136 + ch * 8);
        *(us8*)(Hout + (size_t)crow * DH + nt * 128 + ch * 8) = v;
      }
    }
  } else {
    float* t32 = (float*)SH;
    float* Yp = Yout + (size_t)ks * NSLOT * DM;
#pragma unroll
    for (int h = 0; h < 2; h++) {
      if (wc == h) {
#pragma unroll
        for (int n = 0; n < 4; n++)
#pragma unroll
          for (int m = 0; m < 4; m++)
#pragma unroll
            for (int j = 0; j < 4; j++) {
              int row = wr * 64 + m * 16 + khalf * 4 + j;
              t32[row * 68 + n * 16 + l15] = acc[m][n][j];
            }
      }
      asm volatile("s_waitcnt lgkmcnt(0)" ::: "memory");
      __builtin_amdgcn_s_barrier();
#pragma unroll
      for (int p = 0; p < 8; p++) {
        int c = p * 256 + tid;
        int row = c >> 4, ch = c & 15;
        int crow = m0 + row + hbase;
        if (crow <= cmax) {
          fl4 v = *(const fl4*)(t32 + row * 68 + ch * 4);
          *(fl4*)(Yp + (size_t)crow * DM + nt * 128 + h * 64 + ch * 4) = v;
        }
      }
      if (h == 0) __builtin_amdgcn_s_barrier();
    }
  }
#undef STAGE
#undef COMPUTE
}

extern "C" void kernel_launch(void* const* d_in, const int* in_sizes, int n_in,
                              void* d_out, int out_size, void* d_ws, size_t ws_size,
                              hipStream_t stream) {
  const float* x  = (const float*)d_in[0];
  const float* rw = (const float*)d_in[1];
  const float* w1 = (const float*)d_in[2];
  const float* b1 = (const float*)d_in[3];
  const float* w2 = (const float*)d_in[4];
  const float* b2 = (const float*)d_in[5];
  float* out = (float*)d_out;

  char* ws = (char*)d_ws;
  size_t off = 0;
  u16* xg  = (u16*)(ws + off); off += (size_t)NSLOT * DM * 2;   // 16.8 MB
  u16* H   = (u16*)(ws + off); off += (size_t)NSLOT * DH * 2;   // 67.1 MB
  u16* w1b = (u16*)(ws + off); off += WELEMS * 2;               // 67.1 MB
  u16* w2b = (u16*)(ws + off); off += WELEMS * 2;               // 67.1 MB
  int* tok_map_c = (int*)(ws + off); off += (size_t)NSLOT * 4;
  int* tok_e     = (int*)(ws + off); off += (size_t)T_TOK * 8;
  float* tok_w   = (float*)(ws + off); off += (size_t)T_TOK * 8;
  int* islot     = (int*)(ws + off); off += (size_t)T_TOK * 8;
  int* ctl       = (int*)(ws + off); off += 512;
  float* y0 = (float*)w1b;                    // overlay (w1b dead after fc1)
  float* y1 = y0 + (size_t)NSLOT * DM;

  router_conv_kernel<<<CONVB + T_TOK / 4, 256, 0, stream>>>(
      x, rw, tok_e, tok_w, w1, w1b);
  scanassign_kernel<<<1, 1024, 0, stream>>>(tok_e, ctl, tok_map_c, islot);
  gather_kernel<<<NSLOT / 2, 256, 0, stream>>>(x, tok_map_c, xg);

  moe_gemm<true><<<3072, 256, 0, stream>>>(
      xg, w1b, b1, H, nullptr, ctl, w2, w2b);
  moe_gemm<false><<<8 * 9 * 16, 256, 0, stream>>>(
      H, w2b, nullptr, nullptr, y0, ctl, nullptr, nullptr);
  combine_kernel<<<T_TOK * DM / 4 / 256, 256, 0, stream>>>(
      y0, y1, b2, tok_e, islot, tok_w, out);
}

// Round 19
// 321.889 us; speedup vs baseline: 1.6552x; 1.0024x over previous
//
#include <hip/hip_runtime.h>
#include <hip/hip_bf16.h>

#define T_TOK 4096
#define DM 1024
#define DH 4096
#define NE 8
#define NSLOT (T_TOK * 2)            // compact slots: exactly sum(cnt)
#define MAXTILES 72
#define WELEMS ((size_t)NE * DH * DM)
#define CONVB 768                    // w1-conv filler blocks in router kernel
#define CONVB2 384                   // w2-conv filler blocks in fc1 kernel

typedef __attribute__((ext_vector_type(4))) float fl4;
typedef __attribute__((ext_vector_type(8))) short sh8;
typedef __attribute__((ext_vector_type(8))) unsigned short us8;
typedef unsigned short u16;

__device__ __forceinline__ u16 f2bf(float f) {
  __hip_bfloat16 h = __float2bfloat16(f);
  return __builtin_bit_cast(u16, h);
}

__device__ __forceinline__ float bf2f(u16 u) {
  unsigned int b = (unsigned int)u << 16;
  return __builtin_bit_cast(float, b);
}

__device__ __forceinline__ float gelu_tanh(float x) {
  float u = 0.7978845608028654f * (x + 0.044715f * x * x * x);
  u = fminf(fmaxf(u, -15.f), 15.f);
  float ez = __expf(2.f * u);
  return 0.5f * x * (1.f + (ez - 1.f) / (ez + 1.f));
}

__device__ __forceinline__ void gload_lds16(const void* g, void* l) {
  __builtin_amdgcn_global_load_lds(
      (const __attribute__((address_space(1))) unsigned int*)g,
      (__attribute__((address_space(3))) unsigned int*)l, 16, 0, 0);
}

template <int N>
__device__ __forceinline__ void wait_vmcnt() {
  if constexpr (N == 0) asm volatile("s_waitcnt vmcnt(0)" ::: "memory");
  else if constexpr (N == 4) asm volatile("s_waitcnt vmcnt(4)" ::: "memory");
}

// ---------------- router + w1 conversion filler ----------------
__global__ __launch_bounds__(256) void router_conv_kernel(
    const float* __restrict__ x, const float* __restrict__ rw,
    int* __restrict__ tok_e, float* __restrict__ tok_w,
    const float* __restrict__ w1, u16* __restrict__ w1b) {
  int bid = blockIdx.x;
  int tid = threadIdx.x;
  if (bid < CONVB) {
    size_t stride = (size_t)CONVB * 256 * 8;
    for (size_t i = ((size_t)bid * 256 + tid) * 8; i < WELEMS; i += stride) {
      fl4 a0 = *(const fl4*)(w1 + i);
      fl4 a1 = *(const fl4*)(w1 + i + 4);
      us8 oa;
#pragma unroll
      for (int j = 0; j < 4; j++) { oa[j] = f2bf(a0[j]); oa[j + 4] = f2bf(a1[j]); }
      *(us8*)(w1b + i) = oa;
    }
    return;
  }
  int wv = tid >> 6, lane = tid & 63;
  int t = (bid - CONVB) * 4 + wv;
  if (t >= T_TOK) return;

  const float* xp = x + (size_t)t * DM + lane * 16;
  fl4 xq[4];
#pragma unroll
  for (int i = 0; i < 4; i++) xq[i] = *(const fl4*)(xp + i * 4);

  float acc8[NE];
#pragma unroll
  for (int e = 0; e < NE; e++) {
    const float* wp = rw + (size_t)e * DM + lane * 16;
    float s = 0.f;
#pragma unroll
    for (int i = 0; i < 4; i++) {
      fl4 w4 = *(const fl4*)(wp + i * 4);
      s += xq[i][0] * w4[0] + xq[i][1] * w4[1] + xq[i][2] * w4[2] + xq[i][3] * w4[3];
    }
    acc8[e] = s;
  }
#pragma unroll
  for (int e = 0; e < NE; e++) {
#pragma unroll
    for (int off = 32; off > 0; off >>= 1) acc8[e] += __shfl_xor(acc8[e], off);
  }
  if (lane == 0) {
    float v1 = -1e30f, v2 = -1e30f;
    int i1 = 0, i2 = 0;
#pragma unroll
    for (int e = 0; e < NE; e++) {
      float v = acc8[e];
      if (v > v1) { v2 = v1; i2 = i1; v1 = v; i1 = e; }
      else if (v > v2) { v2 = v; i2 = e; }
    }
    float ex = expf(v2 - v1);
    float s = 1.0f + ex;
    tok_e[t * 2] = i1; tok_e[t * 2 + 1] = i2;
    tok_w[t * 2] = 1.0f / s; tok_w[t * 2 + 1] = ex / s;
  }
}

// ---------------- scanassign (1 block x 1024) ----------------
__global__ __launch_bounds__(1024) void scanassign_kernel(
    const int* __restrict__ tok_e, int* __restrict__ ctl,
    int* __restrict__ tok_map_c, int* __restrict__ islot) {
  __shared__ int cnt_s[NE], cur_s[NE];
  __shared__ int base_s[NE], cbase_s[NE], tb_s[NE + 1];
  int tid = threadIdx.x;
  if (tid < NE) cnt_s[tid] = 0;
  __syncthreads();
  for (int i = tid; i < T_TOK * 2; i += 1024)
    atomicAdd(&cnt_s[tok_e[i]], 1);
  __syncthreads();
  if (tid == 0) {
    int s = 0, cs = 0, tb = 0;
    for (int e = 0; e < NE; e++) {
      base_s[e] = s;
      cbase_s[e] = cs;
      tb_s[e] = tb;
      int c = cnt_s[e];
      int nte = (c + 127) >> 7;
      tb += nte;
      s += nte << 7;
      cs += c;
    }
    tb_s[NE] = tb;
  }
  __syncthreads();
  if (tid < NE) {
    ctl[tid] = cnt_s[tid];
    ctl[16 + tid] = base_s[tid];
    ctl[24 + tid] = cbase_s[tid];
    cur_s[tid] = cbase_s[tid];
  }
  if (tid >= 32 && tid < 32 + MAXTILES) {
    int tt = tid - 32;
    int e = -1;
#pragma unroll
    for (int k = 0; k < NE; k++)
      if (tt >= tb_s[k] && tt < tb_s[k + 1]) e = k;
    ctl[32 + tt] = e;
  }
  __syncthreads();
  for (int t = tid; t < T_TOK; t += 1024) {
#pragma unroll
    for (int k = 0; k < 2; k++) {
      int e = tok_e[t * 2 + k];
      int c = atomicAdd(&cur_s[e], 1);
      tok_map_c[c] = t;
      islot[t * 2 + k] = c;
    }
  }
}

// gather: xg[c] = bf16(x[tok_map_c[c]])
__global__ __launch_bounds__(256) void gather_kernel(
    const float* __restrict__ x, const int* __restrict__ tok_map_c,
    u16* __restrict__ xg) {
  int c = blockIdx.x * 2 + (threadIdx.x >> 7);
  int li = threadIdx.x & 127;
  int t = tok_map_c[c];
  const float* xp = x + (size_t)t * DM + li * 8;
  fl4 v0 = *(const fl4*)xp;
  fl4 v1 = *(const fl4*)(xp + 4);
  us8 o;
#pragma unroll
  for (int j = 0; j < 4; j++) { o[j] = f2bf(v0[j]); o[j + 4] = f2bf(v1[j]); }
  *(us8*)(xg + (size_t)c * DM + li * 8) = o;
}

// combine: out[t] = sum_k w_k * (y0[s_k] + y1[s_k] + b2[e_k]); y bf16, 8/thread
__global__ __launch_bounds__(256) void combine_kernel(
    const u16* __restrict__ y0, const u16* __restrict__ y1,
    const float* __restrict__ b2, const int* __restrict__ tok_e,
    const int* __restrict__ islot, const float* __restrict__ tok_w,
    float* __restrict__ out) {
  int idx = blockIdx.x * 256 + threadIdx.x;
  int t = idx >> 7;
  int c8 = (idx & 127) * 8;
  int e0 = tok_e[t * 2], e1 = tok_e[t * 2 + 1];
  int s0 = islot[t * 2], s1 = islot[t * 2 + 1];
  float w0 = tok_w[t * 2], w1 = tok_w[t * 2 + 1];
  us8 a0 = *(const us8*)(y0 + (size_t)s0 * DM + c8);
  us8 a1 = *(const us8*)(y1 + (size_t)s0 * DM + c8);
  us8 c0 = *(const us8*)(y0 + (size_t)s1 * DM + c8);
  us8 c1 = *(const us8*)(y1 + (size_t)s1 * DM + c8);
  fl4 bb0a = *(const fl4*)(b2 + (size_t)e0 * DM + c8);
  fl4 bb0b = *(const fl4*)(b2 + (size_t)e0 * DM + c8 + 4);
  fl4 bb1a = *(const fl4*)(b2 + (size_t)e1 * DM + c8);
  fl4 bb1b = *(const fl4*)(b2 + (size_t)e1 * DM + c8 + 4);
  fl4 oA, oB;
#pragma unroll
  for (int i = 0; i < 4; i++) {
    oA[i] = w0 * (bf2f(a0[i]) + bf2f(a1[i]) + bb0a[i]) +
            w1 * (bf2f(c0[i]) + bf2f(c1[i]) + bb1a[i]);
    oB[i] = w0 * (bf2f(a0[i + 4]) + bf2f(a1[i + 4]) + bb0b[i]) +
            w1 * (bf2f(c0[i + 4]) + bf2f(c1[i + 4]) + bb1b[i]);
  }
  *(fl4*)(out + (size_t)t * DM + c8) = oA;
  *(fl4*)(out + (size_t)t * DM + c8 + 4) = oB;
}

// ---- grouped GEMM: 128x128, BK=32, 4 waves, counted-vmcnt dbuf loop +
// LDS-repack epilogue. FC1 carries w2-conv filler (1/7 of groups).
// FC2 writes bf16 y partials (single-pass repack).
template <bool FC1>
__global__ __launch_bounds__(256, 4) void moe_gemm(
    const u16* __restrict__ Ab, const u16* __restrict__ Wb,
    const float* __restrict__ bias, u16* __restrict__ Hout,
    u16* __restrict__ Yout, const int* __restrict__ ctl,
    const float* __restrict__ cw_src, u16* __restrict__ cw_dst) {
  constexpr int KTOT = FC1 ? DM : DH;
  constexpr int NTOT = FC1 ? DH : DM;
  constexpr int NKL = FC1 ? 32 : 64;

  __shared__ char SH[36864];

  int bid = blockIdx.x;
  int tid = threadIdx.x;
  int g;
  if (FC1) {
    int gg = bid >> 3;          // [0, 336)
    int r7 = gg % 7;
    if (r7 == 6) {
      // ---- w2 conversion filler block (cb in [0, CONVB2)) ----
      int cb = (gg / 7) * 8 + (bid & 7);
      size_t stride = (size_t)CONVB2 * 256 * 8;
      for (size_t i = ((size_t)cb * 256 + tid) * 8; i < WELEMS; i += stride) {
        fl4 a0 = *(const fl4*)(cw_src + i);
        fl4 a1 = *(const fl4*)(cw_src + i + 4);
        us8 oa;
#pragma unroll
        for (int j = 0; j < 4; j++) { oa[j] = f2bf(a0[j]); oa[j + 4] = f2bf(a1[j]); }
        *(us8*)(cw_dst + i) = oa;
      }
      return;
    }
    g = ((gg / 7) * 6 + r7) * 8 + (bid & 7);   // [0, 2304)
  } else {
    g = bid;
  }

  int x = g & 7, idx = g >> 3;
  int tl = idx % 9, pn = idx / 9;
  int nt, ks;
  if (FC1) { nt = pn; ks = 0; }
  else     { nt = pn >> 1; ks = pn & 1; }
  int tile = x * 9 + tl;

  int e = ctl[32 + tile];
  if (e < 0) return;
  int cnt = ctl[e], base = ctl[16 + e], cbase = ctl[24 + e];
  int hbase = cbase - base;
  int cmax = cbase + cnt - 1;
  int m0 = tile * 128;

  int wv = tid >> 6, lane = tid & 63;
  int wr = wv >> 1, wc = wv & 1;
  int khalf = lane >> 4, l15 = lane & 15;

  const u16* asrc[2];
  const u16* bsrc[2];
#pragma unroll
  for (int r2 = 0; r2 < 2; r2++) {
    int c = r2 * 256 + tid;
    int row = c >> 2, q = c & 3;
    int qs = q ^ ((row >> 2) & 3);
    int crow = m0 + row + hbase;
    if (crow > cmax) crow = cmax;
    asrc[r2] = Ab + (size_t)crow * KTOT + ks * 2048 + qs * 8;
    bsrc[r2] = Wb + ((size_t)e * NTOT + nt * 128 + row) * KTOT + ks * 2048 + qs * 8;
  }

#define STAGE(B, KT)                                                           \
  { _Pragma("unroll") for (int r2 = 0; r2 < 2; r2++) {                         \
      gload_lds16(asrc[r2] + (KT) * 32,                                        \
                  SH + (B) * 8192 + (r2 * 256 + wv * 64) * 16);                \
      gload_lds16(bsrc[r2] + (KT) * 32,                                        \
                  SH + 16384 + (B) * 8192 + (r2 * 256 + wv * 64) * 16);        \
    } }

  int aoff[4], boff[4];
#pragma unroll
  for (int m = 0; m < 4; m++) {
    int rowl = wr * 64 + m * 16 + l15;
    aoff[m] = rowl * 64 + ((khalf * 16) ^ ((rowl & 12) << 2));
  }
#pragma unroll
  for (int n = 0; n < 4; n++) {
    int coll = wc * 64 + n * 16 + l15;
    boff[n] = coll * 64 + ((khalf * 16) ^ ((coll & 12) << 2));
  }

  fl4 acc[4][4];
#pragma unroll
  for (int m = 0; m < 4; m++)
#pragma unroll
    for (int n = 0; n < 4; n++) acc[m][n] = (fl4){0.f, 0.f, 0.f, 0.f};

#define COMPUTE(B)                                                             \
  {                                                                            \
    sh8 af[4], bfr[4];                                                         \
    _Pragma("unroll") for (int m = 0; m < 4; m++)                              \
      af[m] = *(const sh8*)(SH + (B) * 8192 + aoff[m]);                        \
    _Pragma("unroll") for (int n = 0; n < 4; n++)                              \
      bfr[n] = *(const sh8*)(SH + 16384 + (B) * 8192 + boff[n]);               \
    __builtin_amdgcn_s_setprio(1);                                             \
    _Pragma("unroll") for (int m = 0; m < 4; m++)                              \
    _Pragma("unroll") for (int n = 0; n < 4; n++)                              \
      acc[m][n] = __builtin_amdgcn_mfma_f32_16x16x32_bf16(af[m], bfr[n],       \
                                                          acc[m][n], 0, 0, 0); \
    __builtin_amdgcn_s_setprio(0);                                             \
  }

  STAGE(0, 0);
  for (int kt = 0; kt < NKL; kt += 2) {
    STAGE(1, kt + 1);
    wait_vmcnt<4>();
    __builtin_amdgcn_s_barrier();
    COMPUTE(0);
    __builtin_amdgcn_s_barrier();
    if (kt + 2 < NKL) {
      STAGE(0, kt + 2);
      wait_vmcnt<4>();
    } else {
      wait_vmcnt<0>();
    }
    __builtin_amdgcn_s_barrier();
    COMPUTE(1);
    __builtin_amdgcn_s_barrier();
  }

  // epilogue: full 128x128 bf16 tile repack in LDS (stride 136), coalesced us8
  u16* t16 = (u16*)SH;
#pragma unroll
  for (int n = 0; n < 4; n++) {
    int col = wc * 64 + n * 16 + l15;
    float bn = FC1 ? bias[(size_t)e * DH + nt * 128 + col] : 0.f;
#pragma unroll
    for (int m = 0; m < 4; m++)
#pragma unroll
      for (int j = 0; j < 4; j++) {
        int row = wr * 64 + m * 16 + khalf * 4 + j;
        float v = acc[m][n][j];
        t16[row * 136 + col] = f2bf(FC1 ? gelu_tanh(v + bn) : v);
      }
  }
  asm volatile("s_waitcnt lgkmcnt(0)" ::: "memory");
  __builtin_amdgcn_s_barrier();
  u16* dst = FC1 ? Hout : (Yout + (size_t)ks * NSLOT * DM);
  size_t dstride = FC1 ? DH : DM;
#pragma unroll
  for (int p = 0; p < 8; p++) {
    int c = p * 256 + tid;
    int row = c >> 4, ch = c & 15;
    int crow = m0 + row + hbase;
    if (crow <= cmax) {
      us8 v = *(const us8*)(t16 + row * 136 + ch * 8);
      *(us8*)(dst + (size_t)crow * dstride + nt * 128 + ch * 8) = v;
    }
  }
#undef STAGE
#undef COMPUTE
}

extern "C" void kernel_launch(void* const* d_in, const int* in_sizes, int n_in,
                              void* d_out, int out_size, void* d_ws, size_t ws_size,
                              hipStream_t stream) {
  const float* x  = (const float*)d_in[0];
  const float* rw = (const float*)d_in[1];
  const float* w1 = (const float*)d_in[2];
  const float* b1 = (const float*)d_in[3];
  const float* w2 = (const float*)d_in[4];
  const float* b2 = (const float*)d_in[5];
  float* out = (float*)d_out;

  char* ws = (char*)d_ws;
  size_t off = 0;
  u16* xg  = (u16*)(ws + off); off += (size_t)NSLOT * DM * 2;   // 16.8 MB
  u16* H   = (u16*)(ws + off); off += (size_t)NSLOT * DH * 2;   // 67.1 MB
  u16* w1b = (u16*)(ws + off); off += WELEMS * 2;               // 67.1 MB
  u16* w2b = (u16*)(ws + off); off += WELEMS * 2;               // 67.1 MB
  int* tok_map_c = (int*)(ws + off); off += (size_t)NSLOT * 4;
  int* tok_e     = (int*)(ws + off); off += (size_t)T_TOK * 8;
  float* tok_w   = (float*)(ws + off); off += (size_t)T_TOK * 8;
  int* islot     = (int*)(ws + off); off += (size_t)T_TOK * 8;
  int* ctl       = (int*)(ws + off); off += 512;
  // y0,y1 (compact bf16, 16.8 MB each) overlay w1b (dead after fc1)
  u16* y0 = w1b;
  u16* y1 = y0 + (size_t)NSLOT * DM;

  router_conv_kernel<<<CONVB + T_TOK / 4, 256, 0, stream>>>(
      x, rw, tok_e, tok_w, w1, w1b);
  scanassign_kernel<<<1, 1024, 0, stream>>>(tok_e, ctl, tok_map_c, islot);
  gather_kernel<<<NSLOT / 2, 256, 0, stream>>>(x, tok_map_c, xg);

  // fc1: 288 GEMM groups + 48 conv groups (every 7th) = 336 groups = 2688 blk
  moe_gemm<true><<<2688, 256, 0, stream>>>(
      xg, w1b, b1, H, nullptr, ctl, w2, w2b);
  moe_gemm<false><<<8 * 9 * 16, 256, 0, stream>>>(
      H, w2b, nullptr, nullptr, y0, ctl, nullptr, nullptr);
  combine_kernel<<<T_TOK * DM / 8 / 256, 256, 0, stream>>>(
      y0, y1, b2, tok_e, islot, tok_w, out);
}

// Round 20
// 310.012 us; speedup vs baseline: 1.7186x; 1.0383x over previous
//
#include <hip/hip_runtime.h>
#include <hip/hip_bf16.h>

#define T_TOK 4096
#define DM 1024
#define DH 4096
#define NE 8
#define NSLOT (T_TOK * 2)            // compact slots: exactly sum(cnt)
#define MAXTILES 72
#define WELEMS ((size_t)NE * DH * DM)
#define CONVB 768                    // w1-conv filler blocks in router kernel
#define CONVB2 768                   // w2-conv filler blocks in fc1 kernel (1/4)

typedef __attribute__((ext_vector_type(4))) float fl4;
typedef __attribute__((ext_vector_type(8))) short sh8;
typedef __attribute__((ext_vector_type(8))) unsigned short us8;
typedef unsigned short u16;

__device__ __forceinline__ u16 f2bf(float f) {
  __hip_bfloat16 h = __float2bfloat16(f);
  return __builtin_bit_cast(u16, h);
}

__device__ __forceinline__ float bf2f(u16 u) {
  unsigned int b = (unsigned int)u << 16;
  return __builtin_bit_cast(float, b);
}

__device__ __forceinline__ float gelu_tanh(float x) {
  float u = 0.7978845608028654f * (x + 0.044715f * x * x * x);
  u = fminf(fmaxf(u, -15.f), 15.f);
  float ez = __expf(2.f * u);
  return 0.5f * x * (1.f + (ez - 1.f) / (ez + 1.f));
}

__device__ __forceinline__ void gload_lds16(const void* g, void* l) {
  __builtin_amdgcn_global_load_lds(
      (const __attribute__((address_space(1))) unsigned int*)g,
      (__attribute__((address_space(3))) unsigned int*)l, 16, 0, 0);
}

template <int N>
__device__ __forceinline__ void wait_vmcnt() {
  if constexpr (N == 0) asm volatile("s_waitcnt vmcnt(0)" ::: "memory");
  else if constexpr (N == 4) asm volatile("s_waitcnt vmcnt(4)" ::: "memory");
}

// ---------------- router + w1 conversion filler ----------------
__global__ __launch_bounds__(256) void router_conv_kernel(
    const float* __restrict__ x, const float* __restrict__ rw,
    int* __restrict__ tok_e, float* __restrict__ tok_w,
    const float* __restrict__ w1, u16* __restrict__ w1b) {
  int bid = blockIdx.x;
  int tid = threadIdx.x;
  if (bid < CONVB) {
    size_t stride = (size_t)CONVB * 256 * 8;
    for (size_t i = ((size_t)bid * 256 + tid) * 8; i < WELEMS; i += stride) {
      fl4 a0 = *(const fl4*)(w1 + i);
      fl4 a1 = *(const fl4*)(w1 + i + 4);
      us8 oa;
#pragma unroll
      for (int j = 0; j < 4; j++) { oa[j] = f2bf(a0[j]); oa[j + 4] = f2bf(a1[j]); }
      *(us8*)(w1b + i) = oa;
    }
    return;
  }
  int wv = tid >> 6, lane = tid & 63;
  int t = (bid - CONVB) * 4 + wv;
  if (t >= T_TOK) return;

  const float* xp = x + (size_t)t * DM + lane * 16;
  fl4 xq[4];
#pragma unroll
  for (int i = 0; i < 4; i++) xq[i] = *(const fl4*)(xp + i * 4);

  float acc8[NE];
#pragma unroll
  for (int e = 0; e < NE; e++) {
    const float* wp = rw + (size_t)e * DM + lane * 16;
    float s = 0.f;
#pragma unroll
    for (int i = 0; i < 4; i++) {
      fl4 w4 = *(const fl4*)(wp + i * 4);
      s += xq[i][0] * w4[0] + xq[i][1] * w4[1] + xq[i][2] * w4[2] + xq[i][3] * w4[3];
    }
    acc8[e] = s;
  }
#pragma unroll
  for (int e = 0; e < NE; e++) {
#pragma unroll
    for (int off = 32; off > 0; off >>= 1) acc8[e] += __shfl_xor(acc8[e], off);
  }
  if (lane == 0) {
    float v1 = -1e30f, v2 = -1e30f;
    int i1 = 0, i2 = 0;
#pragma unroll
    for (int e = 0; e < NE; e++) {
      float v = acc8[e];
      if (v > v1) { v2 = v1; i2 = i1; v1 = v; i1 = e; }
      else if (v > v2) { v2 = v; i2 = e; }
    }
    float ex = expf(v2 - v1);
    float s = 1.0f + ex;
    tok_e[t * 2] = i1; tok_e[t * 2 + 1] = i2;
    tok_w[t * 2] = 1.0f / s; tok_w[t * 2 + 1] = ex / s;
  }
}

// ---------------- scanassign (1 block x 1024) ----------------
__global__ __launch_bounds__(1024) void scanassign_kernel(
    const int* __restrict__ tok_e, int* __restrict__ ctl,
    int* __restrict__ tok_map_c, int* __restrict__ islot) {
  __shared__ int cnt_s[NE], cur_s[NE];
  __shared__ int base_s[NE], cbase_s[NE], tb_s[NE + 1];
  int tid = threadIdx.x;
  if (tid < NE) cnt_s[tid] = 0;
  __syncthreads();
  for (int i = tid; i < T_TOK * 2; i += 1024)
    atomicAdd(&cnt_s[tok_e[i]], 1);
  __syncthreads();
  if (tid == 0) {
    int s = 0, cs = 0, tb = 0;
    for (int e = 0; e < NE; e++) {
      base_s[e] = s;
      cbase_s[e] = cs;
      tb_s[e] = tb;
      int c = cnt_s[e];
      int nte = (c + 127) >> 7;
      tb += nte;
      s += nte << 7;
      cs += c;
    }
    tb_s[NE] = tb;
  }
  __syncthreads();
  if (tid < NE) {
    ctl[tid] = cnt_s[tid];
    ctl[16 + tid] = base_s[tid];
    ctl[24 + tid] = cbase_s[tid];
    cur_s[tid] = cbase_s[tid];
  }
  if (tid >= 32 && tid < 32 + MAXTILES) {
    int tt = tid - 32;
    int e = -1;
#pragma unroll
    for (int k = 0; k < NE; k++)
      if (tt >= tb_s[k] && tt < tb_s[k + 1]) e = k;
    ctl[32 + tt] = e;
  }
  __syncthreads();
  for (int t = tid; t < T_TOK; t += 1024) {
#pragma unroll
    for (int k = 0; k < 2; k++) {
      int e = tok_e[t * 2 + k];
      int c = atomicAdd(&cur_s[e], 1);
      tok_map_c[c] = t;
      islot[t * 2 + k] = c;
    }
  }
}

// gather: xg[c] = bf16(x[tok_map_c[c]])
__global__ __launch_bounds__(256) void gather_kernel(
    const float* __restrict__ x, const int* __restrict__ tok_map_c,
    u16* __restrict__ xg) {
  int c = blockIdx.x * 2 + (threadIdx.x >> 7);
  int li = threadIdx.x & 127;
  int t = tok_map_c[c];
  const float* xp = x + (size_t)t * DM + li * 8;
  fl4 v0 = *(const fl4*)xp;
  fl4 v1 = *(const fl4*)(xp + 4);
  us8 o;
#pragma unroll
  for (int j = 0; j < 4; j++) { o[j] = f2bf(v0[j]); o[j + 4] = f2bf(v1[j]); }
  *(us8*)(xg + (size_t)c * DM + li * 8) = o;
}

// combine: out[t] = sum_k w_k * (y0[s_k] + y1[s_k] + b2[e_k]); y bf16, 8/thread
__global__ __launch_bounds__(256) void combine_kernel(
    const u16* __restrict__ y0, const u16* __restrict__ y1,
    const float* __restrict__ b2, const int* __restrict__ tok_e,
    const int* __restrict__ islot, const float* __restrict__ tok_w,
    float* __restrict__ out) {
  int idx = blockIdx.x * 256 + threadIdx.x;
  int t = idx >> 7;
  int c8 = (idx & 127) * 8;
  int e0 = tok_e[t * 2], e1 = tok_e[t * 2 + 1];
  int s0 = islot[t * 2], s1 = islot[t * 2 + 1];
  float w0 = tok_w[t * 2], w1 = tok_w[t * 2 + 1];
  us8 a0 = *(const us8*)(y0 + (size_t)s0 * DM + c8);
  us8 a1 = *(const us8*)(y1 + (size_t)s0 * DM + c8);
  us8 c0 = *(const us8*)(y0 + (size_t)s1 * DM + c8);
  us8 c1 = *(const us8*)(y1 + (size_t)s1 * DM + c8);
  fl4 bb0a = *(const fl4*)(b2 + (size_t)e0 * DM + c8);
  fl4 bb0b = *(const fl4*)(b2 + (size_t)e0 * DM + c8 + 4);
  fl4 bb1a = *(const fl4*)(b2 + (size_t)e1 * DM + c8);
  fl4 bb1b = *(const fl4*)(b2 + (size_t)e1 * DM + c8 + 4);
  fl4 oA, oB;
#pragma unroll
  for (int i = 0; i < 4; i++) {
    oA[i] = w0 * (bf2f(a0[i]) + bf2f(a1[i]) + bb0a[i]) +
            w1 * (bf2f(c0[i]) + bf2f(c1[i]) + bb1a[i]);
    oB[i] = w0 * (bf2f(a0[i + 4]) + bf2f(a1[i + 4]) + bb0b[i]) +
            w1 * (bf2f(c0[i + 4]) + bf2f(c1[i + 4]) + bb1b[i]);
  }
  *(fl4*)(out + (size_t)t * DM + c8) = oA;
  *(fl4*)(out + (size_t)t * DM + c8 + 4) = oB;
}

// ---- grouped GEMM: 128x128, BK=32, 4 waves, counted-vmcnt dbuf loop +
// LDS-repack epilogue. FC1 carries w2-conv filler (1/4 of groups, r17-proven).
// FC2 writes bf16 y partials (single-pass repack).
template <bool FC1>
__global__ __launch_bounds__(256, 4) void moe_gemm(
    const u16* __restrict__ Ab, const u16* __restrict__ Wb,
    const float* __restrict__ bias, u16* __restrict__ Hout,
    u16* __restrict__ Yout, const int* __restrict__ ctl,
    const float* __restrict__ cw_src, u16* __restrict__ cw_dst) {
  constexpr int KTOT = FC1 ? DM : DH;
  constexpr int NTOT = FC1 ? DH : DM;
  constexpr int NKL = FC1 ? 32 : 64;

  __shared__ char SH[36864];

  int bid = blockIdx.x;
  int tid = threadIdx.x;
  int g;
  if (FC1) {
    int gg = bid >> 3;          // [0, 384)
    if ((gg & 3) == 3) {
      // ---- w2 conversion filler block (cb in [0, CONVB2)) ----
      int cb = (gg >> 2) * 8 + (bid & 7);
      size_t stride = (size_t)CONVB2 * 256 * 8;
      for (size_t i = ((size_t)cb * 256 + tid) * 8; i < WELEMS; i += stride) {
        fl4 a0 = *(const fl4*)(cw_src + i);
        fl4 a1 = *(const fl4*)(cw_src + i + 4);
        us8 oa;
#pragma unroll
        for (int j = 0; j < 4; j++) { oa[j] = f2bf(a0[j]); oa[j + 4] = f2bf(a1[j]); }
        *(us8*)(cw_dst + i) = oa;
      }
      return;
    }
    g = ((gg >> 2) * 3 + (gg & 3)) * 8 + (bid & 7);   // [0, 2304)
  } else {
    g = bid;
  }

  int x = g & 7, idx = g >> 3;
  int tl = idx % 9, pn = idx / 9;
  int nt, ks;
  if (FC1) { nt = pn; ks = 0; }
  else     { nt = pn >> 1; ks = pn & 1; }
  int tile = x * 9 + tl;

  int e = ctl[32 + tile];
  if (e < 0) return;
  int cnt = ctl[e], base = ctl[16 + e], cbase = ctl[24 + e];
  int hbase = cbase - base;
  int cmax = cbase + cnt - 1;
  int m0 = tile * 128;

  int wv = tid >> 6, lane = tid & 63;
  int wr = wv >> 1, wc = wv & 1;
  int khalf = lane >> 4, l15 = lane & 15;

  const u16* asrc[2];
  const u16* bsrc[2];
#pragma unroll
  for (int r2 = 0; r2 < 2; r2++) {
    int c = r2 * 256 + tid;
    int row = c >> 2, q = c & 3;
    int qs = q ^ ((row >> 2) & 3);
    int crow = m0 + row + hbase;
    if (crow > cmax) crow = cmax;
    asrc[r2] = Ab + (size_t)crow * KTOT + ks * 2048 + qs * 8;
    bsrc[r2] = Wb + ((size_t)e * NTOT + nt * 128 + row) * KTOT + ks * 2048 + qs * 8;
  }

#define STAGE(B, KT)                                                           \
  { _Pragma("unroll") for (int r2 = 0; r2 < 2; r2++) {                         \
      gload_lds16(asrc[r2] + (KT) * 32,                                        \
                  SH + (B) * 8192 + (r2 * 256 + wv * 64) * 16);                \
      gload_lds16(bsrc[r2] + (KT) * 32,                                        \
                  SH + 16384 + (B) * 8192 + (r2 * 256 + wv * 64) * 16);        \
    } }

  int aoff[4], boff[4];
#pragma unroll
  for (int m = 0; m < 4; m++) {
    int rowl = wr * 64 + m * 16 + l15;
    aoff[m] = rowl * 64 + ((khalf * 16) ^ ((rowl & 12) << 2));
  }
#pragma unroll
  for (int n = 0; n < 4; n++) {
    int coll = wc * 64 + n * 16 + l15;
    boff[n] = coll * 64 + ((khalf * 16) ^ ((coll & 12) << 2));
  }

  fl4 acc[4][4];
#pragma unroll
  for (int m = 0; m < 4; m++)
#pragma unroll
    for (int n = 0; n < 4; n++) acc[m][n] = (fl4){0.f, 0.f, 0.f, 0.f};

#define COMPUTE(B)                                                             \
  {                                                                            \
    sh8 af[4], bfr[4];                                                         \
    _Pragma("unroll") for (int m = 0; m < 4; m++)                              \
      af[m] = *(const sh8*)(SH + (B) * 8192 + aoff[m]);                        \
    _Pragma("unroll") for (int n = 0; n < 4; n++)                              \
      bfr[n] = *(const sh8*)(SH + 16384 + (B) * 8192 + boff[n]);               \
    __builtin_amdgcn_s_setprio(1);                                             \
    _Pragma("unroll") for (int m = 0; m < 4; m++)                              \
    _Pragma("unroll") for (int n = 0; n < 4; n++)                              \
      acc[m][n] = __builtin_amdgcn_mfma_f32_16x16x32_bf16(af[m], bfr[n],       \
                                                          acc[m][n], 0, 0, 0); \
    __builtin_amdgcn_s_setprio(0);                                             \
  }

  STAGE(0, 0);
  for (int kt = 0; kt < NKL; kt += 2) {
    STAGE(1, kt + 1);
    wait_vmcnt<4>();
    __builtin_amdgcn_s_barrier();
    COMPUTE(0);
    __builtin_amdgcn_s_barrier();
    if (kt + 2 < NKL) {
      STAGE(0, kt + 2);
      wait_vmcnt<4>();
    } else {
      wait_vmcnt<0>();
    }
    __builtin_amdgcn_s_barrier();
    COMPUTE(1);
    __builtin_amdgcn_s_barrier();
  }

  // epilogue: full 128x128 bf16 tile repack in LDS (stride 136), coalesced us8
  u16* t16 = (u16*)SH;
#pragma unroll
  for (int n = 0; n < 4; n++) {
    int col = wc * 64 + n * 16 + l15;
    float bn = FC1 ? bias[(size_t)e * DH + nt * 128 + col] : 0.f;
#pragma unroll
    for (int m = 0; m < 4; m++)
#pragma unroll
      for (int j = 0; j < 4; j++) {
        int row = wr * 64 + m * 16 + khalf * 4 + j;
        float v = acc[m][n][j];
        t16[row * 136 + col] = f2bf(FC1 ? gelu_tanh(v + bn) : v);
      }
  }
  asm volatile("s_waitcnt lgkmcnt(0)" ::: "memory");
  __builtin_amdgcn_s_barrier();
  u16* dst = FC1 ? Hout : (Yout + (size_t)ks * NSLOT * DM);
  size_t dstride = FC1 ? DH : DM;
#pragma unroll
  for (int p = 0; p < 8; p++) {
    int c = p * 256 + tid;
    int row = c >> 4, ch = c & 15;
    int crow = m0 + row + hbase;
    if (crow <= cmax) {
      us8 v = *(const us8*)(t16 + row * 136 + ch * 8);
      *(us8*)(dst + (size_t)crow * dstride + nt * 128 + ch * 8) = v;
    }
  }
#undef STAGE
#undef COMPUTE
}

extern "C" void kernel_launch(void* const* d_in, const int* in_sizes, int n_in,
                              void* d_out, int out_size, void* d_ws, size_t ws_size,
                              hipStream_t stream) {
  const float* x  = (const float*)d_in[0];
  const float* rw = (const float*)d_in[1];
  const float* w1 = (const float*)d_in[2];
  const float* b1 = (const float*)d_in[3];
  const float* w2 = (const float*)d_in[4];
  const float* b2 = (const float*)d_in[5];
  float* out = (float*)d_out;

  char* ws = (char*)d_ws;
  size_t off = 0;
  u16* xg  = (u16*)(ws + off); off += (size_t)NSLOT * DM * 2;   // 16.8 MB
  u16* H   = (u16*)(ws + off); off += (size_t)NSLOT * DH * 2;   // 67.1 MB
  u16* w1b = (u16*)(ws + off); off += WELEMS * 2;               // 67.1 MB
  u16* w2b = (u16*)(ws + off); off += WELEMS * 2;               // 67.1 MB
  int* tok_map_c = (int*)(ws + off); off += (size_t)NSLOT * 4;
  int* tok_e     = (int*)(ws + off); off += (size_t)T_TOK * 8;
  float* tok_w   = (float*)(ws + off); off += (size_t)T_TOK * 8;
  int* islot     = (int*)(ws + off); off += (size_t)T_TOK * 8;
  int* ctl       = (int*)(ws + off); off += 512;
  // y0,y1 (compact bf16, 16.8 MB each) overlay w1b (dead after fc1)
  u16* y0 = w1b;
  u16* y1 = y0 + (size_t)NSLOT * DM;

  router_conv_kernel<<<CONVB + T_TOK / 4, 256, 0, stream>>>(
      x, rw, tok_e, tok_w, w1, w1b);
  scanassign_kernel<<<1, 1024, 0, stream>>>(tok_e, ctl, tok_map_c, islot);
  gather_kernel<<<NSLOT / 2, 256, 0, stream>>>(x, tok_map_c, xg);

  // fc1: 288 GEMM groups + 96 conv groups (every 4th) = 384 groups = 3072 blk
  moe_gemm<true><<<3072, 256, 0, stream>>>(
      xg, w1b, b1, H, nullptr, ctl, w2, w2b);
  moe_gemm<false><<<8 * 9 * 16, 256, 0, stream>>>(
      H, w2b, nullptr, nullptr, y0, ctl, nullptr, nullptr);
  combine_kernel<<<T_TOK * DM / 8 / 256, 256, 0, stream>>>(
      y0, y1, b2, tok_e, islot, tok_w, out);
}